// Round 10
// baseline (5593.755 us; speedup 1.0000x reference)
//
#include <hip/hip_runtime.h>
#include <cstdint>

// ---------------------------------------------------------------------------
// Frustum-PointNet forward, MI355X. R10 = R9 fp64 pipeline, diagnostics
// removed, and sampling switched to JAX *partitionable* threefry
// (default since jax 0.4.36): u[i] from block ctr=(0,i), bits = w0 ^ w1.
// ---------------------------------------------------------------------------

constexpr int PP   = 65536;   // B*N
constexpr int PP2  = 16384;   // B*M
constexpr int OUTW = 4158;

constexpr size_t D_Y1  = 0;
constexpr size_t D_Y2  = (size_t)64 * PP;
constexpr size_t D_Y3  = (size_t)128 * PP;
constexpr size_t D_Y4  = (size_t)192 * PP;
constexpr size_t D_C5S = 0;
constexpr size_t D_C5Q = (size_t)16 * PP;
constexpr size_t D_C5M = (size_t)32 * PP;
constexpr size_t D_S1S = 0;
constexpr size_t D_S1Q = (size_t)8 * PP;
constexpr size_t D_S1M = (size_t)16 * PP;
constexpr size_t D_S2  = (size_t)128 * PP;
constexpr size_t D_S3  = 0;
constexpr size_t D_S4  = (size_t)128 * PP;
constexpr size_t DREGION = (size_t)384 * PP;

constexpr size_t F_T1 = 0;
constexpr size_t F_T2 = F_T1 + (size_t)128 * PP2;
constexpr size_t F_PT = F_T2 + (size_t)256 * PP2;
constexpr size_t F_B1 = F_PT + (size_t)5 * 256 * 512;
constexpr size_t F_B2 = F_B1 + (size_t)128 * PP2;
constexpr size_t F_B3 = F_B2 + (size_t)128 * PP2;
constexpr size_t F_PB = F_B3 + (size_t)256 * PP2;
static_assert(F_PB + (size_t)5 * 256 * 512 <= 2 * DREGION, "t/b overlay overflow");

constexpr size_t P0       = 2 * DREGION;
constexpr size_t F_MASK   = P0;
constexpr size_t F_MIDX   = F_MASK + PP;
constexpr size_t F_CNT    = F_MIDX + PP;
constexpr size_t F_MEANV  = F_CNT + 32;
constexpr size_t F_OBJ    = F_MEANV + 96;
constexpr size_t F_GVT    = F_OBJ + (size_t)3 * PP2;
constexpr size_t F_GVB    = F_GVT + 32 * 515;
constexpr size_t F_YT1    = F_GVB + 32 * 515;
constexpr size_t F_YT2    = F_YT1 + 32 * 256;
constexpr size_t F_YB1    = F_YT2 + 32 * 128;
constexpr size_t F_YB2    = F_YB1 + 32 * 512;
constexpr size_t F_CD     = F_YB2 + 32 * 256;
constexpr size_t F_GVECD  = F_CD + 96;
static_assert((F_GVECD % 2) == 0, "double align");
constexpr size_t F_GDOTD  = F_GVECD + 65728;
constexpr size_t F_STD    = F_GDOTD + 32768;
constexpr size_t F_END    = F_STD + 81920;
constexpr size_t NEED_BYTES = F_END * 4;

// ---------------------------------------------------------------------------
__global__ __launch_bounds__(256) void conv_pc_d(const float* __restrict__ pc,
                                                 const float* __restrict__ W,
                                                 const float* __restrict__ bias,
                                                 double* __restrict__ Y) {
  int p = blockIdx.x * 256 + threadIdx.x;
  int o = blockIdx.y;
  float4 v = *reinterpret_cast<const float4*>(&pc[(size_t)p * 4]);
  double s = (double)bias[o] + (double)v.x * (double)W[o * 4 + 0] +
             (double)v.y * (double)W[o * 4 + 1] + (double)v.z * (double)W[o * 4 + 2] +
             (double)v.w * (double)W[o * 4 + 3];
  Y[(size_t)o * PP + p] = s;
}

template <bool FUSED>
__global__ __launch_bounds__(256) void dconv_gemm_k(
    const double* __restrict__ X, int ldx, const float* __restrict__ W, int ldw, int C,
    const float* __restrict__ bias, const double* __restrict__ scale,
    const double* __restrict__ shift, int relu_in, const double* __restrict__ gadd,
    double* __restrict__ Y, int Ptot, double* __restrict__ psum, double* __restrict__ psq,
    double* __restrict__ pmax, int Ototal) {
  __shared__ double Xs[16][64];
  __shared__ double Ws[64][17];
  const int tid = threadIdx.x;
  const int tx = tid & 15, ty = tid >> 4;
  const int o0 = blockIdx.x * 64, p0 = blockIdx.y * 64;
  double acc[4][4] = {};
  for (int c0 = 0; c0 < C; c0 += 16) {
#pragma unroll
    for (int j = 0; j < 4; ++j) {
      int idx = tid + j * 256;
      int k = idx >> 6, n = idx & 63;
      int c = c0 + k;
      double v = 0.0;
      if (c < C) {
        v = X[(size_t)c * ldx + p0 + n];
        if (scale) v = v * scale[c] + shift[c];
        if (relu_in && v < 0.0) v = 0.0;
      }
      Xs[k][n] = v;
    }
#pragma unroll
    for (int j = 0; j < 4; ++j) {
      int idx = tid + j * 256;
      int o = idx >> 4, k = idx & 15;
      int c = c0 + k;
      Ws[o][k] = (c < C) ? (double)W[(size_t)(o0 + o) * ldw + c] : 0.0;
    }
    __syncthreads();
#pragma unroll
    for (int k = 0; k < 16; ++k) {
      double bx[4], aw[4];
#pragma unroll
      for (int j = 0; j < 4; ++j) bx[j] = Xs[k][tx * 4 + j];
#pragma unroll
      for (int i = 0; i < 4; ++i) aw[i] = Ws[ty * 4 + i][k];
#pragma unroll
      for (int i = 0; i < 4; ++i)
#pragma unroll
        for (int j = 0; j < 4; ++j) acc[i][j] = fma(aw[i], bx[j], acc[i][j]);
    }
    __syncthreads();
  }
#pragma unroll
  for (int i = 0; i < 4; ++i) {
    int o = o0 + ty * 4 + i;
    double badd = bias ? (double)bias[o] : 0.0;
    if (gadd) badd += gadd[o * 32 + (p0 >> 11)];
#pragma unroll
    for (int j = 0; j < 4; ++j) acc[i][j] += badd;
  }
  if constexpr (!FUSED) {
#pragma unroll
    for (int i = 0; i < 4; ++i) {
      int o = o0 + ty * 4 + i;
#pragma unroll
      for (int j = 0; j < 4; ++j) Y[(size_t)o * Ptot + p0 + tx * 4 + j] = acc[i][j];
    }
  } else {
    __shared__ double redd[16][64];
#pragma unroll
    for (int i = 0; i < 4; ++i)
      redd[tx][ty * 4 + i] = acc[i][0] + acc[i][1] + acc[i][2] + acc[i][3];
    __syncthreads();
    if (tid < 64) {
      double s = 0.0;
      for (int t = 0; t < 16; ++t) s += redd[t][tid];
      psum[(size_t)blockIdx.y * Ototal + o0 + tid] = s;
    }
    __syncthreads();
#pragma unroll
    for (int i = 0; i < 4; ++i)
      redd[tx][ty * 4 + i] = acc[i][0] * acc[i][0] + acc[i][1] * acc[i][1] +
                             acc[i][2] * acc[i][2] + acc[i][3] * acc[i][3];
    __syncthreads();
    if (tid < 64) {
      double s = 0.0;
      for (int t = 0; t < 16; ++t) s += redd[t][tid];
      psq[(size_t)blockIdx.y * Ototal + o0 + tid] = s;
    }
    __syncthreads();
#pragma unroll
    for (int i = 0; i < 4; ++i) {
      double m0 = acc[i][0] > acc[i][1] ? acc[i][0] : acc[i][1];
      double m1 = acc[i][2] > acc[i][3] ? acc[i][2] : acc[i][3];
      redd[tx][ty * 4 + i] = m0 > m1 ? m0 : m1;
    }
    __syncthreads();
    if (tid < 64) {
      double s = -1.0e300;
      for (int t = 0; t < 16; ++t) s = s > redd[t][tid] ? s : redd[t][tid];
      pmax[(size_t)blockIdx.y * Ototal + o0 + tid] = s;
    }
  }
}

__global__ __launch_bounds__(256) void s2_fused_k(
    const double* __restrict__ Y2, const float* __restrict__ W1,
    const float* __restrict__ W2, const float* __restrict__ bias2,
    const double* __restrict__ sc2, const double* __restrict__ sh2,
    const double* __restrict__ sc1, const double* __restrict__ sh1,
    const double* __restrict__ gdot, double* __restrict__ S2) {
  __shared__ double pf[64][64];
  __shared__ double S1a[16][64];
  __shared__ double Ws[64][17];
  const int tid = threadIdx.x;
  const int tx = tid & 15, ty = tid >> 4;
  const int o0 = blockIdx.x * 64, p0 = blockIdx.y * 64;
  const int b = p0 >> 11;
  for (int j = 0; j < 16; ++j) {
    int idx = tid + j * 256;
    int cc = idx >> 6, n = idx & 63;
    double v = Y2[(size_t)cc * PP + p0 + n] * sc2[cc] + sh2[cc];
    pf[cc][n] = v > 0.0 ? v : 0.0;
  }
  __syncthreads();
  double acc[4][4] = {};
  for (int c0 = 0; c0 < 512; c0 += 16) {
#pragma unroll
    for (int j = 0; j < 4; ++j) {
      int idx = tid + j * 256;
      int cl = idx >> 6, n = idx & 63;
      int c = c0 + cl;
      const float* w1r = W1 + (size_t)c * 1091 + 1027;
      double raw = gdot[c * 32 + b];
      for (int cc = 0; cc < 64; ++cc) raw += pf[cc][n] * (double)w1r[cc];
      double v = raw * sc1[c] + sh1[c];
      S1a[cl][n] = v > 0.0 ? v : 0.0;
    }
#pragma unroll
    for (int j = 0; j < 4; ++j) {
      int idx = tid + j * 256;
      int o = idx >> 4, k = idx & 15;
      Ws[o][k] = (double)W2[(size_t)(o0 + o) * 512 + c0 + k];
    }
    __syncthreads();
#pragma unroll
    for (int k = 0; k < 16; ++k) {
      double bx[4], aw[4];
#pragma unroll
      for (int j = 0; j < 4; ++j) bx[j] = S1a[k][tx * 4 + j];
#pragma unroll
      for (int i = 0; i < 4; ++i) aw[i] = Ws[ty * 4 + i][k];
#pragma unroll
      for (int i = 0; i < 4; ++i)
#pragma unroll
        for (int j = 0; j < 4; ++j) acc[i][j] = fma(aw[i], bx[j], acc[i][j]);
    }
    __syncthreads();
  }
#pragma unroll
  for (int i = 0; i < 4; ++i) {
    int o = o0 + ty * 4 + i;
    double bd = (double)bias2[o];
#pragma unroll
    for (int j = 0; j < 4; ++j) S2[(size_t)o * PP + p0 + tx * 4 + j] = acc[i][j] + bd;
  }
}

__global__ __launch_bounds__(256) void dstats_k(const double* __restrict__ Y, int Ptot,
                                                double* __restrict__ scale,
                                                double* __restrict__ shift) {
  int o = blockIdx.x;
  const double* row = Y + (size_t)o * Ptot;
  double s = 0.0, q = 0.0;
  for (int p = threadIdx.x; p < Ptot; p += 256) {
    double v = row[p];
    s += v; q += v * v;
  }
  __shared__ double ss[256], qq[256];
  int tid = threadIdx.x;
  ss[tid] = s; qq[tid] = q;
  __syncthreads();
  for (int off = 128; off; off >>= 1) {
    if (tid < off) { ss[tid] += ss[tid + off]; qq[tid] += qq[tid + off]; }
    __syncthreads();
  }
  if (tid == 0) {
    double m = ss[0] / (double)Ptot;
    double v = qq[0] / (double)Ptot - m * m;
    if (v < 0.0) v = 0.0;
    double sc = 1.0 / sqrt(v + 1e-5);
    scale[o] = sc;
    shift[o] = -m * sc;
  }
}

__global__ __launch_bounds__(256) void fstats_k(const float* __restrict__ Y, int Ptot,
                                                double* __restrict__ scale,
                                                double* __restrict__ shift) {
  int o = blockIdx.x;
  const float* row = Y + (size_t)o * Ptot;
  double s = 0.0, q = 0.0;
  for (int p = threadIdx.x; p < Ptot; p += 256) {
    double v = (double)row[p];
    s += v; q += v * v;
  }
  __shared__ double ss[256], qq[256];
  int tid = threadIdx.x;
  ss[tid] = s; qq[tid] = q;
  __syncthreads();
  for (int off = 128; off; off >>= 1) {
    if (tid < off) { ss[tid] += ss[tid + off]; qq[tid] += qq[tid + off]; }
    __syncthreads();
  }
  if (tid == 0) {
    double m = ss[0] / (double)Ptot;
    double v = qq[0] / (double)Ptot - m * m;
    if (v < 0.0) v = 0.0;
    double sc = 1.0 / sqrt(v + 1e-5);
    scale[o] = sc;
    shift[o] = -m * sc;
  }
}

__global__ void dstats_reduce_k(const double* __restrict__ psum,
                                const double* __restrict__ psq, int ntiles, int O,
                                double invP, double* __restrict__ scale,
                                double* __restrict__ shift) {
  int o = blockIdx.x * blockDim.x + threadIdx.x;
  if (o >= O) return;
  double s = 0.0, q = 0.0;
  for (int t = 0; t < ntiles; ++t) {
    s += psum[(size_t)t * O + o];
    q += psq[(size_t)t * O + o];
  }
  double m = s * invP;
  double v = q * invP - m * m;
  if (v < 0.0) v = 0.0;
  double sc = 1.0 / sqrt(v + 1e-5);
  scale[o] = sc;
  shift[o] = -m * sc;
}

__global__ void maxpool_g_d(const double* __restrict__ pmax, int tilesPB, int O,
                            const double* __restrict__ scale, const double* __restrict__ shift,
                            int relu, double* __restrict__ out, int ostride, int ooff) {
  int idx = blockIdx.x * blockDim.x + threadIdx.x;
  if (idx >= 32 * O) return;
  int b = idx / O, o = idx - b * O;
  double m = -1.0e300;
  for (int t = b * tilesPB; t < (b + 1) * tilesPB; ++t) {
    double v = pmax[(size_t)t * O + o];
    if (v > m) m = v;
  }
  double v = scale[o] * m + shift[o];
  if (relu && v < 0.0) v = 0.0;
  out[(size_t)b * ostride + ooff + o] = v;
}

__global__ void maxpool_g_f(const float* __restrict__ pmax, int tilesPB, int O,
                            const double* __restrict__ scale, const double* __restrict__ shift,
                            int relu, float* __restrict__ out, int ostride, int ooff) {
  int idx = blockIdx.x * blockDim.x + threadIdx.x;
  if (idx >= 32 * O) return;
  int b = idx / O, o = idx - b * O;
  float m = -3.402823466e38f;
  for (int t = b * tilesPB; t < (b + 1) * tilesPB; ++t) m = fmaxf(m, pmax[(size_t)t * O + o]);
  double v = scale[o] * (double)m + shift[o];
  if (relu && v < 0.0) v = 0.0;
  out[(size_t)b * ostride + ooff + o] = (float)v;
}

__global__ void onehot_k(const float* __restrict__ oh, double* __restrict__ gvecD,
                         float* __restrict__ gvt, float* __restrict__ gvb) {
  int i = threadIdx.x;
  if (i >= 96) return;
  int b = i / 3, c = i - b * 3;
  float v = oh[b * 3 + c];
  gvecD[b * 1027 + c] = (double)v;
  gvt[b * 515 + c] = v;
  gvb[b * 515 + 512 + c] = v;
}

__global__ void gdot_d(const float* __restrict__ W, const double* __restrict__ gvec,
                       double* __restrict__ gdot) {
  int idx = blockIdx.x * 256 + threadIdx.x;
  int o = idx >> 5, b = idx & 31;
  double s = 0.0;
  const float* wr = W + (size_t)o * 1091;
  const double* gr = gvec + (size_t)b * 1027;
  for (int c = 0; c < 1027; ++c) s += (double)wr[c] * gr[c];
  gdot[o * 32 + b] = s;
}

__global__ __launch_bounds__(256) void logits_d(const double* __restrict__ S4,
                                                const float* __restrict__ W,
                                                const float* __restrict__ bias,
                                                const double* __restrict__ scale,
                                                const double* __restrict__ shift,
                                                float* __restrict__ out,
                                                int* __restrict__ mask) {
  int p = blockIdx.x * 256 + threadIdx.x;
  double l0 = (double)bias[0], l1 = (double)bias[1];
  for (int c = 0; c < 128; ++c) {
    double v = S4[(size_t)c * PP + p] * scale[c] + shift[c];
    if (v < 0.0) v = 0.0;
    l0 += v * (double)W[c];
    l1 += v * (double)W[128 + c];
  }
  int b = p >> 11, n = p & 2047;
  out[(size_t)b * OUTW + 2 * n] = (float)l0;
  out[(size_t)b * OUTW + 2 * n + 1] = (float)l1;
  mask[p] = (l0 < l1) ? 1 : 0;
}

__global__ __launch_bounds__(256) void compact_k(const int* __restrict__ mask,
                                                 const float* __restrict__ pc,
                                                 int* __restrict__ midx, int* __restrict__ cnt,
                                                 float* __restrict__ meanv) {
  int b = blockIdx.x, tid = threadIdx.x;
  __shared__ int sc[256];
  __shared__ int base;
  __shared__ double red[256];
  __shared__ double totals[3];
  if (tid == 0) base = 0;
  __syncthreads();
  double sx = 0.0, sy = 0.0, sz = 0.0;
  for (int n0 = 0; n0 < 2048; n0 += 256) {
    int n = n0 + tid;
    int mval = mask[b * 2048 + n];
    sc[tid] = mval;
    __syncthreads();
    for (int off = 1; off < 256; off <<= 1) {
      int v = (tid >= off) ? sc[tid - off] : 0;
      __syncthreads();
      sc[tid] += v;
      __syncthreads();
    }
    int excl = sc[tid] - mval;
    if (mval) {
      midx[b * 2048 + base + excl] = n;
      const float* q = &pc[((size_t)(b * 2048 + n)) * 4];
      sx += (double)q[0]; sy += (double)q[1]; sz += (double)q[2];
    }
    __syncthreads();
    if (tid == 0) base += sc[255];
    __syncthreads();
  }
  red[tid] = sx; __syncthreads();
  for (int off = 128; off; off >>= 1) { if (tid < off) red[tid] += red[tid + off]; __syncthreads(); }
  if (tid == 0) totals[0] = red[0];
  __syncthreads();
  red[tid] = sy; __syncthreads();
  for (int off = 128; off; off >>= 1) { if (tid < off) red[tid] += red[tid + off]; __syncthreads(); }
  if (tid == 0) totals[1] = red[0];
  __syncthreads();
  red[tid] = sz; __syncthreads();
  for (int off = 128; off; off >>= 1) { if (tid < off) red[tid] += red[tid + off]; __syncthreads(); }
  if (tid == 0) {
    totals[2] = red[0];
    int c = base;
    cnt[b] = c;
    double d = (double)(c > 1 ? c : 1);
    meanv[b * 3 + 0] = (float)(totals[0] / d);
    meanv[b * 3 + 1] = (float)(totals[1] / d);
    meanv[b * 3 + 2] = (float)(totals[2] / d);
  }
}

// --------------------------- threefry2x32 ----------------------------------
__device__ __forceinline__ uint32_t rotl32(uint32_t x, int r) {
  return (x << r) | (x >> (32 - r));
}
__device__ inline void threefry2x32(uint32_t k0, uint32_t k1, uint32_t& x0, uint32_t& x1) {
  const uint32_t ks[3] = {k0, k1, k0 ^ k1 ^ 0x1BD11BDAu};
  const int rot[2][4] = {{13, 15, 26, 6}, {17, 29, 16, 24}};
  x0 += ks[0]; x1 += ks[1];
  for (int i = 0; i < 5; ++i) {
    const int* r = rot[i & 1];
    for (int j = 0; j < 4; ++j) {
      x0 += x1; x1 = rotl32(x1, r[j]); x1 ^= x0;
    }
    x0 += ks[(i + 1) % 3];
    x1 += ks[(i + 2) % 3] + (uint32_t)(i + 1);
  }
}

// Partitionable threefry sampling (jax default since 0.4.36):
// element e -> 64-bit ctr e -> block threefry2x32(key,(hi=0, lo=e)),
// 32-bit output word = w0 ^ w1.
__global__ void sample_k(const float* __restrict__ pc, const int* __restrict__ midx,
                         const int* __restrict__ cnt, const float* __restrict__ meanv,
                         float* __restrict__ obj) {
  int e = blockIdx.x * 256 + threadIdx.x;
  if (e >= 16384) return;
  uint32_t x0 = 0u, x1 = (uint32_t)e;
  threefry2x32(0u, 42u, x0, x1);
  uint32_t bits = x0 ^ x1;
  float u = __uint_as_float((bits >> 9) | 0x3F800000u) - 1.0f;
  int b = e >> 9;
  int m = e & 511;
  int c_ = cnt[b];
  int pos = (int)(u * (float)c_);   // fp32 product + trunc, faithful to ref
  int cap = c_ - 1; if (cap < 0) cap = 0;
  if (pos > cap) pos = cap;
  float vx = 0.f, vy = 0.f, vz = 0.f;
  if (c_ > 0) {
    int n = midx[b * 2048 + pos];
    const float* q = &pc[((size_t)(b * 2048 + n)) * 4];
    vx = q[0] - meanv[b * 3 + 0];
    vy = q[1] - meanv[b * 3 + 1];
    vz = q[2] - meanv[b * 3 + 2];
  }
  int p2 = b * 512 + m;
  obj[p2] = vx;
  obj[PP2 + p2] = vy;
  obj[2 * PP2 + p2] = vz;
}

__global__ __launch_bounds__(256) void conv_k3_k(const float* __restrict__ Xc,
                                                 const float* __restrict__ W,
                                                 const float* __restrict__ bias,
                                                 const float* __restrict__ cd,
                                                 float* __restrict__ Y) {
  int p = blockIdx.x * 256 + threadIdx.x;
  int o = blockIdx.y;
  int b = p >> 9;
  double x0 = Xc[p], x1 = Xc[PP2 + p], x2 = Xc[2 * PP2 + p];
  if (cd) { x0 -= (double)cd[b * 3]; x1 -= (double)cd[b * 3 + 1]; x2 -= (double)cd[b * 3 + 2]; }
  double s = (double)bias[o] + x0 * (double)W[o * 3] + x1 * (double)W[o * 3 + 1] +
             x2 * (double)W[o * 3 + 2];
  Y[(size_t)o * PP2 + p] = (float)s;
}

template <bool FUSED>
__global__ __launch_bounds__(256) void fconv_gemm_k(
    const float* __restrict__ X, int ldx, const float* __restrict__ W, int ldw, int C,
    const float* __restrict__ bias, const double* __restrict__ scale,
    const double* __restrict__ shift, int relu_in,
    float* __restrict__ Y, int Ptot, double* __restrict__ psum, double* __restrict__ psq,
    float* __restrict__ pmax, int Ototal) {
  __shared__ double Xs[16][64];
  __shared__ double Ws[64][17];
  const int tid = threadIdx.x;
  const int tx = tid & 15, ty = tid >> 4;
  const int o0 = blockIdx.x * 64, p0 = blockIdx.y * 64;
  double acc[4][4] = {};
  for (int c0 = 0; c0 < C; c0 += 16) {
#pragma unroll
    for (int j = 0; j < 4; ++j) {
      int idx = tid + j * 256;
      int k = idx >> 6, n = idx & 63;
      int c = c0 + k;
      double v = 0.0;
      if (c < C) {
        v = (double)X[(size_t)c * ldx + p0 + n];
        if (scale) v = v * scale[c] + shift[c];
        if (relu_in && v < 0.0) v = 0.0;
      }
      Xs[k][n] = v;
    }
#pragma unroll
    for (int j = 0; j < 4; ++j) {
      int idx = tid + j * 256;
      int o = idx >> 4, k = idx & 15;
      int c = c0 + k;
      Ws[o][k] = (c < C) ? (double)W[(size_t)(o0 + o) * ldw + c] : 0.0;
    }
    __syncthreads();
#pragma unroll
    for (int k = 0; k < 16; ++k) {
      double bx[4], aw[4];
#pragma unroll
      for (int j = 0; j < 4; ++j) bx[j] = Xs[k][tx * 4 + j];
#pragma unroll
      for (int i = 0; i < 4; ++i) aw[i] = Ws[ty * 4 + i][k];
#pragma unroll
      for (int i = 0; i < 4; ++i)
#pragma unroll
        for (int j = 0; j < 4; ++j) acc[i][j] = fma(aw[i], bx[j], acc[i][j]);
    }
    __syncthreads();
  }
#pragma unroll
  for (int i = 0; i < 4; ++i) {
    int o = o0 + ty * 4 + i;
    double badd = bias ? (double)bias[o] : 0.0;
#pragma unroll
    for (int j = 0; j < 4; ++j) acc[i][j] += badd;
  }
  if constexpr (!FUSED) {
#pragma unroll
    for (int i = 0; i < 4; ++i) {
      int o = o0 + ty * 4 + i;
#pragma unroll
      for (int j = 0; j < 4; ++j)
        Y[(size_t)o * Ptot + p0 + tx * 4 + j] = (float)acc[i][j];
    }
  } else {
    __shared__ double redd[16][64];
#pragma unroll
    for (int i = 0; i < 4; ++i)
      redd[tx][ty * 4 + i] = acc[i][0] + acc[i][1] + acc[i][2] + acc[i][3];
    __syncthreads();
    if (tid < 64) {
      double s = 0.0;
      for (int t = 0; t < 16; ++t) s += redd[t][tid];
      psum[(size_t)blockIdx.y * Ototal + o0 + tid] = s;
    }
    __syncthreads();
#pragma unroll
    for (int i = 0; i < 4; ++i)
      redd[tx][ty * 4 + i] = acc[i][0] * acc[i][0] + acc[i][1] * acc[i][1] +
                             acc[i][2] * acc[i][2] + acc[i][3] * acc[i][3];
    __syncthreads();
    if (tid < 64) {
      double s = 0.0;
      for (int t = 0; t < 16; ++t) s += redd[t][tid];
      psq[(size_t)blockIdx.y * Ototal + o0 + tid] = s;
    }
    __syncthreads();
#pragma unroll
    for (int i = 0; i < 4; ++i) {
      double m0 = acc[i][0] > acc[i][1] ? acc[i][0] : acc[i][1];
      double m1 = acc[i][2] > acc[i][3] ? acc[i][2] : acc[i][3];
      redd[tx][ty * 4 + i] = m0 > m1 ? m0 : m1;
    }
    __syncthreads();
    if (tid < 64) {
      double s = -1.0e300;
      for (int t = 0; t < 16; ++t) s = s > redd[t][tid] ? s : redd[t][tid];
      pmax[(size_t)blockIdx.y * Ototal + o0 + tid] = (float)s;
    }
  }
}

__global__ void fc_gemm_k(const float* __restrict__ Xf, int ldx, int K,
                          const float* __restrict__ W, const float* __restrict__ bias,
                          const double* __restrict__ scale, const double* __restrict__ shift,
                          int relu, float* __restrict__ Y, int ldy, int yoff, int O) {
  int o = blockIdx.x * blockDim.x + threadIdx.x;
  int b = blockIdx.y;
  if (o >= O) return;
  const float* x = Xf + (size_t)b * ldx;
  const float* w = W + (size_t)o * K;
  double s = bias ? (double)bias[o] : 0.0;
  for (int k = 0; k < K; ++k) {
    double v = (double)x[k];
    if (scale) {
      v = v * scale[k] + shift[k];
      if (relu && v < 0.0) v = 0.0;
    }
    s += v * (double)w[k];
  }
  Y[(size_t)b * ldy + yoff + o] = (float)s;
}

__global__ void fc_stats_k(const float* __restrict__ Y, int ldy, int O,
                           double* __restrict__ scale, double* __restrict__ shift) {
  int o = blockIdx.x * blockDim.x + threadIdx.x;
  if (o >= O) return;
  double s = 0.0, q = 0.0;
  for (int b = 0; b < 32; ++b) {
    double v = (double)Y[(size_t)b * ldy + o];
    s += v; q += v * v;
  }
  double m = s / 32.0;
  double v = q / 32.0 - m * m;
  if (v < 0.0) v = 0.0;
  double sc = 1.0 / sqrt(v + 1e-5);
  scale[o] = sc;
  shift[o] = -m * sc;
}

__global__ void center_k(float* __restrict__ out, const float* __restrict__ cd,
                         const float* __restrict__ meanv) {
  int i = threadIdx.x;
  if (i >= 96) return;
  int b = i / 3, c = i - b * 3;
  out[(size_t)b * OUTW + 4155 + c] =
      (float)((double)out[(size_t)b * OUTW + 4096 + c] + (double)cd[b * 3 + c] +
              (double)meanv[b * 3 + c]);
}

__global__ void size_fail_k(float* out, float code) {
  if (threadIdx.x == 0 && blockIdx.x == 0) out[0] = code;
}

// ---------------------------------------------------------------------------
extern "C" void kernel_launch(void* const* d_in, const int* in_sizes, int n_in, void* d_out,
                              int out_size, void* d_ws, size_t ws_size, hipStream_t stream) {
  float* out = (float*)d_out;
  static const int EXP[48] = {
      262144, 96, 256, 64, 4096, 64, 4096, 64, 8192, 128, 131072, 1024,
      558592, 512, 131072, 256, 32768, 128, 16384, 128, 256, 2,
      384, 128, 32768, 256, 131072, 512, 131840, 256, 32768, 128, 384, 3,
      384, 128, 16384, 128, 32768, 256, 131072, 512, 263680, 512, 131072, 256,
      15104, 59};
  if (n_in != 48) { size_fail_k<<<1, 1, 0, stream>>>(out, 9.0e6f + 99.0f * 1e4f); return; }
  if (out_size != 133056) { size_fail_k<<<1, 1, 0, stream>>>(out, 9.0e6f + 98.0f * 1e4f); return; }
  for (int i = 0; i < 48; ++i)
    if (in_sizes[i] != EXP[i]) {
      size_fail_k<<<1, 1, 0, stream>>>(out, 9.0e6f + (float)i * 1e4f);
      return;
    }
  if (ws_size < NEED_BYTES) { size_fail_k<<<1, 1, 0, stream>>>(out, 9.0e6f + 97.0f * 1e4f); return; }

  const float* pc = (const float*)d_in[0];
  const float* oh = (const float*)d_in[1];
#define IN(i) ((const float*)d_in[i])
  float* ws = (float*)d_ws;
  double* dws = (double*)d_ws;
  double* STD = (double*)(ws + F_STD);
  auto SC = [&](int s) { return STD + (size_t)s * 2048; };
  auto SH = [&](int s) { return STD + (size_t)s * 2048 + 1024; };
  enum { L_C1, L_C2, L_C3, L_C4, L_C5, L_S1, L_S2, L_S3, L_S4, L_T1, L_T2, L_T3,
         L_B1, L_B2, L_B3, L_B4, L_FT1, L_FT2, L_FB1, L_FB2 };

  double* Y1d = dws + D_Y1;
  double* Y2d = dws + D_Y2;
  double* Y3d = dws + D_Y3;
  double* Y4d = dws + D_Y4;
  double* C5S = dws + D_C5S;
  double* C5Q = dws + D_C5Q;
  double* C5M = dws + D_C5M;
  double* S1S = dws + D_S1S;
  double* S1Q = dws + D_S1Q;
  double* S1M = dws + D_S1M;
  double* S2d = dws + D_S2;
  double* S3d = dws + D_S3;
  double* S4d = dws + D_S4;
  int* mask = (int*)(ws + F_MASK);
  int* midx = (int*)(ws + F_MIDX);
  int* cnt  = (int*)(ws + F_CNT);
  float* meanv = ws + F_MEANV;
  float* obj = ws + F_OBJ;
  float* gvt = ws + F_GVT;
  float* gvb = ws + F_GVB;
  float* yt1 = ws + F_YT1;
  float* yt2 = ws + F_YT2;
  float* yb1 = ws + F_YB1;
  float* yb2 = ws + F_YB2;
  float* cd  = ws + F_CD;
  double* gvecD = (double*)(ws + F_GVECD);
  double* gdotD = (double*)(ws + F_GDOTD);
  float* T1f = ws + F_T1;
  float* T2f = ws + F_T2;
  double* PTs = (double*)(ws + F_PT);
  double* PTq = (double*)(ws + F_PT + (size_t)2 * 256 * 512);
  float*  PTm = ws + F_PT + (size_t)4 * 256 * 512;
  float* B1f = ws + F_B1;
  float* B2f = ws + F_B2;
  float* B3f = ws + F_B3;
  double* PBs = (double*)(ws + F_PB);
  double* PBq = (double*)(ws + F_PB + (size_t)2 * 256 * 512);
  float*  PBm = ws + F_PB + (size_t)4 * 256 * 512;

  dim3 blk(256);
  conv_pc_d<<<dim3(PP / 256, 64), blk, 0, stream>>>(pc, IN(2), IN(3), Y1d);
  dstats_k<<<64, blk, 0, stream>>>(Y1d, PP, SC(L_C1), SH(L_C1));
  dconv_gemm_k<false><<<dim3(1, PP / 64), blk, 0, stream>>>(Y1d, PP, IN(4), 64, 64, IN(5),
      SC(L_C1), SH(L_C1), 1, nullptr, Y2d, PP, nullptr, nullptr, nullptr, 0);
  dstats_k<<<64, blk, 0, stream>>>(Y2d, PP, SC(L_C2), SH(L_C2));
  dconv_gemm_k<false><<<dim3(1, PP / 64), blk, 0, stream>>>(Y2d, PP, IN(6), 64, 64, IN(7),
      SC(L_C2), SH(L_C2), 1, nullptr, Y3d, PP, nullptr, nullptr, nullptr, 0);
  dstats_k<<<64, blk, 0, stream>>>(Y3d, PP, SC(L_C3), SH(L_C3));
  dconv_gemm_k<false><<<dim3(2, PP / 64), blk, 0, stream>>>(Y3d, PP, IN(8), 64, 64, IN(9),
      SC(L_C3), SH(L_C3), 1, nullptr, Y4d, PP, nullptr, nullptr, nullptr, 0);
  dstats_k<<<128, blk, 0, stream>>>(Y4d, PP, SC(L_C4), SH(L_C4));
  dconv_gemm_k<true><<<dim3(16, PP / 64), blk, 0, stream>>>(Y4d, PP, IN(10), 128, 128,
      IN(11), SC(L_C4), SH(L_C4), 1, nullptr, nullptr, PP, C5S, C5Q, C5M, 1024);
  dstats_reduce_k<<<4, blk, 0, stream>>>(C5S, C5Q, 1024, 1024, 1.0 / PP, SC(L_C5), SH(L_C5));
  onehot_k<<<1, 96, 0, stream>>>(oh, gvecD, gvt, gvb);
  maxpool_g_d<<<(32 * 1024) / 256, blk, 0, stream>>>(C5M, 32, 1024, SC(L_C5), SH(L_C5), 0,
                                                     gvecD, 1027, 3);
  gdot_d<<<64, blk, 0, stream>>>(IN(12), gvecD, gdotD);
  dconv_gemm_k<true><<<dim3(8, PP / 64), blk, 0, stream>>>(Y2d, PP, IN(12) + 1027, 1091, 64,
      IN(13), SC(L_C2), SH(L_C2), 1, gdotD, nullptr, PP, S1S, S1Q, S1M, 512);
  dstats_reduce_k<<<2, blk, 0, stream>>>(S1S, S1Q, 1024, 512, 1.0 / PP, SC(L_S1), SH(L_S1));
  s2_fused_k<<<dim3(4, PP / 64), blk, 0, stream>>>(Y2d, IN(12), IN(14), IN(15),
      SC(L_C2), SH(L_C2), SC(L_S1), SH(L_S1), gdotD, S2d);
  dstats_k<<<256, blk, 0, stream>>>(S2d, PP, SC(L_S2), SH(L_S2));
  dconv_gemm_k<false><<<dim3(2, PP / 64), blk, 0, stream>>>(S2d, PP, IN(16), 256, 256,
      IN(17), SC(L_S2), SH(L_S2), 1, nullptr, S3d, PP, nullptr, nullptr, nullptr, 0);
  dstats_k<<<128, blk, 0, stream>>>(S3d, PP, SC(L_S3), SH(L_S3));
  dconv_gemm_k<false><<<dim3(2, PP / 64), blk, 0, stream>>>(S3d, PP, IN(18), 128, 128,
      IN(19), SC(L_S3), SH(L_S3), 1, nullptr, S4d, PP, nullptr, nullptr, nullptr, 0);
  dstats_k<<<128, blk, 0, stream>>>(S4d, PP, SC(L_S4), SH(L_S4));
  logits_d<<<PP / 256, blk, 0, stream>>>(S4d, IN(20), IN(21), SC(L_S4), SH(L_S4), out, mask);
  compact_k<<<32, blk, 0, stream>>>(mask, pc, midx, cnt, meanv);
  sample_k<<<64, blk, 0, stream>>>(pc, midx, cnt, meanv, obj);
  conv_k3_k<<<dim3(PP2 / 256, 128), blk, 0, stream>>>(obj, IN(22), IN(23), nullptr, T1f);
  fstats_k<<<128, blk, 0, stream>>>(T1f, PP2, SC(L_T1), SH(L_T1));
  fconv_gemm_k<false><<<dim3(4, PP2 / 64), blk, 0, stream>>>(T1f, PP2, IN(24), 128, 128,
      IN(25), SC(L_T1), SH(L_T1), 1, T2f, PP2, nullptr, nullptr, nullptr, 0);
  fstats_k<<<256, blk, 0, stream>>>(T2f, PP2, SC(L_T2), SH(L_T2));
  fconv_gemm_k<true><<<dim3(8, PP2 / 64), blk, 0, stream>>>(T2f, PP2, IN(26), 256, 256,
      IN(27), SC(L_T2), SH(L_T2), 1, nullptr, PP2, PTs, PTq, PTm, 512);
  dstats_reduce_k<<<2, blk, 0, stream>>>(PTs, PTq, 256, 512, 1.0 / PP2, SC(L_T3), SH(L_T3));
  maxpool_g_f<<<(32 * 512) / 256, blk, 0, stream>>>(PTm, 8, 512, SC(L_T3), SH(L_T3), 1,
                                                    gvt, 515, 3);
  fc_gemm_k<<<dim3(1, 32), blk, 0, stream>>>(gvt, 515, 515, IN(28), IN(29), nullptr, nullptr,
                                             0, yt1, 256, 0, 256);
  fc_stats_k<<<1, blk, 0, stream>>>(yt1, 256, 256, SC(L_FT1), SH(L_FT1));
  fc_gemm_k<<<dim3(1, 32), blk, 0, stream>>>(yt1, 256, 256, IN(30), IN(31), SC(L_FT1),
                                             SH(L_FT1), 1, yt2, 128, 0, 128);
  fc_stats_k<<<1, blk, 0, stream>>>(yt2, 128, 128, SC(L_FT2), SH(L_FT2));
  fc_gemm_k<<<dim3(1, 32), blk, 0, stream>>>(yt2, 128, 128, IN(32), IN(33), SC(L_FT2),
                                             SH(L_FT2), 1, cd, 3, 0, 3);
  conv_k3_k<<<dim3(PP2 / 256, 128), blk, 0, stream>>>(obj, IN(34), IN(35), cd, B1f);
  fstats_k<<<128, blk, 0, stream>>>(B1f, PP2, SC(L_B1), SH(L_B1));
  fconv_gemm_k<false><<<dim3(2, PP2 / 64), blk, 0, stream>>>(B1f, PP2, IN(36), 128, 128,
      IN(37), SC(L_B1), SH(L_B1), 1, B2f, PP2, nullptr, nullptr, nullptr, 0);
  fstats_k<<<128, blk, 0, stream>>>(B2f, PP2, SC(L_B2), SH(L_B2));
  fconv_gemm_k<false><<<dim3(4, PP2 / 64), blk, 0, stream>>>(B2f, PP2, IN(38), 128, 128,
      IN(39), SC(L_B2), SH(L_B2), 1, B3f, PP2, nullptr, nullptr, nullptr, 0);
  fstats_k<<<256, blk, 0, stream>>>(B3f, PP2, SC(L_B3), SH(L_B3));
  fconv_gemm_k<true><<<dim3(8, PP2 / 64), blk, 0, stream>>>(B3f, PP2, IN(40), 256, 256,
      IN(41), SC(L_B3), SH(L_B3), 1, nullptr, PP2, PBs, PBq, PBm, 512);
  dstats_reduce_k<<<2, blk, 0, stream>>>(PBs, PBq, 256, 512, 1.0 / PP2, SC(L_B4), SH(L_B4));
  maxpool_g_f<<<(32 * 512) / 256, blk, 0, stream>>>(PBm, 8, 512, SC(L_B4), SH(L_B4), 1,
                                                    gvb, 515, 0);
  fc_gemm_k<<<dim3(2, 32), blk, 0, stream>>>(gvb, 515, 515, IN(42), IN(43), nullptr, nullptr,
                                             0, yb1, 512, 0, 512);
  fc_stats_k<<<2, blk, 0, stream>>>(yb1, 512, 512, SC(L_FB1), SH(L_FB1));
  fc_gemm_k<<<dim3(1, 32), blk, 0, stream>>>(yb1, 512, 512, IN(44), IN(45), SC(L_FB1),
                                             SH(L_FB1), 1, yb2, 256, 0, 256);
  fc_stats_k<<<1, blk, 0, stream>>>(yb2, 256, 256, SC(L_FB2), SH(L_FB2));
  fc_gemm_k<<<dim3(1, 32), blk, 0, stream>>>(yb2, 256, 256, IN(46), IN(47), SC(L_FB2),
                                             SH(L_FB2), 1, out, OUTW, 4096, 59);
  center_k<<<1, 96, 0, stream>>>(out, cd, meanv);
#undef IN
}

// Round 11
// 2986.882 us; speedup vs baseline: 1.8728x; 1.8728x over previous
//
#include <hip/hip_runtime.h>
#include <cstdint>

// ---------------------------------------------------------------------------
// Frustum-PointNet forward, MI355X.  R11 = fp32 storage/compute pipeline
// (R2 structure) + fp64-exact stats/logits accumulation + R6 P5-layout fix
// + JAX partitionable threefry sampling (the R10 fix).
// Workspace ~219.7 MB. Evidence chain: R1(fp32) ≡ R6(fp64) bit-identical,
// R10(fp64+partitionable RNG) passed  ⟹  fp32+fixed RNG passes.
// ---------------------------------------------------------------------------

constexpr int PP   = 65536;   // B*N
constexpr int PP2  = 16384;   // B*M
constexpr int OUTW = 4158;    // 2*N + 59 + 3

// ---- big-buffer layout (float offsets), liveness-overlapped ----
constexpr size_t F_Y1 = 0;                       // 64*PP   (dead after conv2)
constexpr size_t F_Y2 = (size_t)64 * PP;         // 64*PP   (pointfeat; live till S1)
constexpr size_t F_Y3 = (size_t)128 * PP;        // 64*PP   (dead after conv4)
constexpr size_t F_Y4 = (size_t)192 * PP;        // 128*PP  (dead after conv5 stats)
// conv5 fused partials: P5s,P5q doubles exactly fill Y1 slot; P5m in dead Y3 slot.
constexpr size_t F_P5S = 0;                          // double[1M] -> [0, 2M floats)
constexpr size_t F_P5Q = (size_t)2 * 1024 * 1024;    // double[1M] -> [2M, 4M floats)
constexpr size_t F_P5M = (size_t)128 * PP;           // float[1M] inside dead Y3 slot
static_assert(F_P5Q + 2 * 1024 * 1024 <= F_Y2, "P5 partials exceed Y1 slot");
static_assert(F_P5M + 1024 * 1024 <= (size_t)192 * PP, "P5m exceeds Y3 slot");
constexpr size_t F_S1 = (size_t)320 * PP;        // 512*PP
constexpr size_t F_S2 = 0;                       // 256*PP  (Y1..Y4 dead)
constexpr size_t F_S3 = (size_t)320 * PP;        // 128*PP  (S1 dead)
constexpr size_t F_S4 = (size_t)448 * PP;        // 128*PP  (live till logits)
// t/b overlay in [0, 256*PP) after logits:
constexpr size_t F_T1 = 0;                                  // 128*PP2
constexpr size_t F_T2 = F_T1 + (size_t)128 * PP2;           // 256*PP2
constexpr size_t F_PT = F_T2 + (size_t)256 * PP2;           // 5*256*512 (2 dbl + 1 flt)
constexpr size_t F_B1 = F_PT + (size_t)5 * 256 * 512;       // 128*PP2
constexpr size_t F_B2 = F_B1 + (size_t)128 * PP2;           // 128*PP2
constexpr size_t F_B3 = F_B2 + (size_t)128 * PP2;           // 256*PP2
constexpr size_t F_PB = F_B3 + (size_t)256 * PP2;           // 5*256*512
static_assert(F_PB + (size_t)5 * 256 * 512 <= (size_t)256 * PP, "t/b overlay overflow");
static_assert((F_PT % 2) == 0 && (F_PB % 2) == 0, "double alignment");

// ---- persistent small region at 832*PP ----
constexpr size_t SB       = (size_t)832 * PP;
constexpr size_t F_MASK   = SB;                    // int[PP]
constexpr size_t F_MIDX   = F_MASK + PP;           // int[PP]
constexpr size_t F_CNT    = F_MIDX + PP;           // int[32]
constexpr size_t F_MEAN   = F_CNT + 32;            // float[96]
constexpr size_t F_GVEC   = F_MEAN + 96;           // 32*1027
constexpr size_t F_GVT    = F_GVEC + 32 * 1027;    // 32*515
constexpr size_t F_GVB    = F_GVT + 32 * 515;      // 32*515
constexpr size_t F_GDOT   = F_GVB + 32 * 515;      // 512*32
constexpr size_t F_YT1    = F_GDOT + 512 * 32;     // 32*256
constexpr size_t F_YT2    = F_YT1 + 32 * 256;      // 32*128
constexpr size_t F_YB1    = F_YT2 + 32 * 128;      // 32*512
constexpr size_t F_YB2    = F_YB1 + 32 * 512;      // 32*256
constexpr size_t F_CD     = F_YB2 + 32 * 256;      // 96
constexpr size_t F_OBJ    = F_CD + 96;             // 3*PP2
constexpr size_t F_ST     = F_OBJ + (size_t)3 * PP2;  // 20 slots * 2048 floats
constexpr size_t F_END    = F_ST + 20 * 2048;
constexpr size_t NEED_BYTES = F_END * 4;           // ~219.7 MB

#define NEG_INF (-3.402823466e38f)

// ---------------------------------------------------------------------------
__global__ __launch_bounds__(256) void conv_pc_k(const float* __restrict__ pc,
                                                 const float* __restrict__ W,
                                                 const float* __restrict__ bias,
                                                 float* __restrict__ Y) {
  int p = blockIdx.x * 256 + threadIdx.x;
  int o = blockIdx.y;
  float4 v = *reinterpret_cast<const float4*>(&pc[(size_t)p * 4]);
  float s = bias[o] + v.x * W[o * 4 + 0] + v.y * W[o * 4 + 1] + v.z * W[o * 4 + 2] +
            v.w * W[o * 4 + 3];
  Y[(size_t)o * PP + p] = s;
}

// K=3 conv for t_w1 / b_w1 (optionally subtract per-batch center_delta)
__global__ __launch_bounds__(256) void conv_k3_k(const float* __restrict__ Xc,
                                                 const float* __restrict__ W,
                                                 const float* __restrict__ bias,
                                                 const float* __restrict__ cd,
                                                 float* __restrict__ Y) {
  int p = blockIdx.x * 256 + threadIdx.x;
  int o = blockIdx.y;
  int b = p >> 9;  // M=512
  float x0 = Xc[p], x1 = Xc[PP2 + p], x2 = Xc[2 * PP2 + p];
  if (cd) { x0 -= cd[b * 3]; x1 -= cd[b * 3 + 1]; x2 -= cd[b * 3 + 2]; }
  Y[(size_t)o * PP2 + p] = bias[o] + x0 * W[o * 3] + x1 * W[o * 3 + 1] + x2 * W[o * 3 + 2];
}

// ---------------------------------------------------------------------------
// fp32 tiled conv-GEMM. Y[o][p] = bias[o](+gadd[o][b]) + sum_c act(X[c][p])*W[o][c]
// act(v) = relu?(v*scale[c]+shift[c]).  grid = (O/64, Ptot/64), block 256.
// FUSED: no Y store; per point-tile partial sum/sumsq (fp64) + max per channel.
template <bool FUSED>
__global__ __launch_bounds__(256) void conv_gemm_k(
    const float* __restrict__ X, int ldx, const float* __restrict__ W, int ldw, int C,
    const float* __restrict__ bias, const float* __restrict__ scale,
    const float* __restrict__ shift, int relu_in, const float* __restrict__ gadd,
    float* __restrict__ Y, int Ptot, double* __restrict__ psum, double* __restrict__ psq,
    float* __restrict__ pmax, int Ototal) {
  __shared__ float Xs[16][64];
  __shared__ float Ws[64][17];
  const int tid = threadIdx.x;
  const int tx = tid & 15, ty = tid >> 4;
  const int o0 = blockIdx.x * 64, p0 = blockIdx.y * 64;
  float acc[4][4] = {};
  for (int c0 = 0; c0 < C; c0 += 16) {
#pragma unroll
    for (int j = 0; j < 4; ++j) {
      int idx = tid + j * 256;
      int k = idx >> 6, n = idx & 63;
      int c = c0 + k;
      float v = 0.f;
      if (c < C) {
        v = X[(size_t)c * ldx + p0 + n];
        if (scale) v = v * scale[c] + shift[c];
        if (relu_in) v = fmaxf(v, 0.f);
      }
      Xs[k][n] = v;
    }
#pragma unroll
    for (int j = 0; j < 4; ++j) {
      int idx = tid + j * 256;
      int o = idx >> 4, k = idx & 15;
      int c = c0 + k;
      Ws[o][k] = (c < C) ? W[(size_t)(o0 + o) * ldw + c] : 0.f;
    }
    __syncthreads();
#pragma unroll
    for (int k = 0; k < 16; ++k) {
      float bx[4], aw[4];
#pragma unroll
      for (int j = 0; j < 4; ++j) bx[j] = Xs[k][tx * 4 + j];
#pragma unroll
      for (int i = 0; i < 4; ++i) aw[i] = Ws[ty * 4 + i][k];
#pragma unroll
      for (int i = 0; i < 4; ++i)
#pragma unroll
        for (int j = 0; j < 4; ++j) acc[i][j] = fmaf(aw[i], bx[j], acc[i][j]);
    }
    __syncthreads();
  }
#pragma unroll
  for (int i = 0; i < 4; ++i) {
    int o = o0 + ty * 4 + i;
    float badd = bias ? bias[o] : 0.f;
    if (gadd) badd += gadd[o * 32 + (p0 >> 11)];  // sh1 only: Ptot==PP, N=2048
#pragma unroll
    for (int j = 0; j < 4; ++j) acc[i][j] += badd;
  }
  if constexpr (!FUSED) {
#pragma unroll
    for (int i = 0; i < 4; ++i) {
      int o = o0 + ty * 4 + i;
      float4 v = make_float4(acc[i][0], acc[i][1], acc[i][2], acc[i][3]);
      *reinterpret_cast<float4*>(&Y[(size_t)o * Ptot + p0 + tx * 4]) = v;
    }
  } else {
    __shared__ double redd[16][64];
    __shared__ float redf[16][64];
#pragma unroll
    for (int i = 0; i < 4; ++i)
      redd[tx][ty * 4 + i] = (double)acc[i][0] + (double)acc[i][1] +
                             (double)acc[i][2] + (double)acc[i][3];
    __syncthreads();
    if (tid < 64) {
      double s = 0.0;
      for (int t = 0; t < 16; ++t) s += redd[t][tid];
      psum[(size_t)blockIdx.y * Ototal + o0 + tid] = s;
    }
    __syncthreads();
#pragma unroll
    for (int i = 0; i < 4; ++i)
      redd[tx][ty * 4 + i] =
          (double)acc[i][0] * (double)acc[i][0] + (double)acc[i][1] * (double)acc[i][1] +
          (double)acc[i][2] * (double)acc[i][2] + (double)acc[i][3] * (double)acc[i][3];
    __syncthreads();
    if (tid < 64) {
      double s = 0.0;
      for (int t = 0; t < 16; ++t) s += redd[t][tid];
      psq[(size_t)blockIdx.y * Ototal + o0 + tid] = s;
    }
    __syncthreads();
#pragma unroll
    for (int i = 0; i < 4; ++i)
      redf[tx][ty * 4 + i] =
          fmaxf(fmaxf(acc[i][0], acc[i][1]), fmaxf(acc[i][2], acc[i][3]));
    __syncthreads();
    if (tid < 64) {
      float s = NEG_INF;
      for (int t = 0; t < 16; ++t) s = fmaxf(s, redf[t][tid]);
      pmax[(size_t)blockIdx.y * Ototal + o0 + tid] = s;
    }
  }
}

// BN stats over stored (O x Ptot) fp32 activation; fp64 accumulation.
__global__ __launch_bounds__(256) void stats_k(const float* __restrict__ Y, int Ptot,
                                               float* __restrict__ scale,
                                               float* __restrict__ shift) {
  int o = blockIdx.x;
  const float* row = Y + (size_t)o * Ptot;
  double s = 0.0, q = 0.0;
  for (int p = threadIdx.x; p < Ptot; p += 256) {
    double v = (double)row[p];
    s += v;
    q += v * v;
  }
  __shared__ double ss[256], qq[256];
  int tid = threadIdx.x;
  ss[tid] = s; qq[tid] = q;
  __syncthreads();
  for (int off = 128; off; off >>= 1) {
    if (tid < off) { ss[tid] += ss[tid + off]; qq[tid] += qq[tid + off]; }
    __syncthreads();
  }
  if (tid == 0) {
    double m = ss[0] / (double)Ptot;
    double v = qq[0] / (double)Ptot - m * m;
    if (v < 0.0) v = 0.0;
    double sc = 1.0 / sqrt(v + 1e-5);
    scale[o] = (float)sc;
    shift[o] = (float)(-m * sc);
  }
}

// BN stats from per-tile fp64 partials (fused layers)
__global__ void stats_reduce_k(const double* __restrict__ psum, const double* __restrict__ psq,
                               int ntiles, int O, double invP, float* __restrict__ scale,
                               float* __restrict__ shift) {
  int o = blockIdx.x * blockDim.x + threadIdx.x;
  if (o >= O) return;
  double s = 0.0, q = 0.0;
  for (int t = 0; t < ntiles; ++t) {
    s += psum[(size_t)t * O + o];
    q += psq[(size_t)t * O + o];
  }
  double m = s * invP;
  double v = q * invP - m * m;
  if (v < 0.0) v = 0.0;
  double sc = 1.0 / sqrt(v + 1e-5);
  scale[o] = (float)sc;
  shift[o] = (float)(-m * sc);
}

// pooled g[b][o] = (relu?)(scale*max + shift)
__global__ void maxpool_g_k(const float* __restrict__ pmax, int tilesPB, int O,
                            const float* __restrict__ scale, const float* __restrict__ shift,
                            int relu, float* __restrict__ out, int ostride, int ooff) {
  int idx = blockIdx.x * blockDim.x + threadIdx.x;
  if (idx >= 32 * O) return;
  int b = idx / O, o = idx - b * O;
  float m = NEG_INF;
  for (int t = b * tilesPB; t < (b + 1) * tilesPB; ++t) m = fmaxf(m, pmax[(size_t)t * O + o]);
  float v = scale[o] * m + shift[o];
  if (relu) v = fmaxf(v, 0.f);
  out[(size_t)b * ostride + ooff + o] = v;
}

__global__ void onehot_k(const float* __restrict__ oh, float* __restrict__ gvec,
                         float* __restrict__ gvt, float* __restrict__ gvb) {
  int i = threadIdx.x;
  if (i >= 96) return;
  int b = i / 3, c = i - b * 3;
  float v = oh[b * 3 + c];
  gvec[b * 1027 + c] = v;
  gvt[b * 515 + c] = v;
  gvb[b * 515 + 512 + c] = v;
}

// gdot[o][b] = sum_{c<1027} sh_w1[o][c] * gvec[b][c]  (fp64 accum, float store)
__global__ void gdot_k(const float* __restrict__ W, const float* __restrict__ gvec,
                       float* __restrict__ gdot) {
  int idx = blockIdx.x * 256 + threadIdx.x;  // 512*32
  int o = idx >> 5, b = idx & 31;
  double s = 0.0;
  const float* wr = W + (size_t)o * 1091;
  const float* gr = gvec + (size_t)b * 1027;
  for (int c = 0; c < 1027; ++c) s += (double)wr[c] * (double)gr[c];
  gdot[o * 32 + b] = (float)s;
}

// logits (sh_w5) + mask; fp64 accumulators over fp32 data
__global__ __launch_bounds__(256) void logits_k(const float* __restrict__ S4,
                                                const float* __restrict__ W,
                                                const float* __restrict__ bias,
                                                const float* __restrict__ scale,
                                                const float* __restrict__ shift,
                                                float* __restrict__ out,
                                                int* __restrict__ mask) {
  int p = blockIdx.x * 256 + threadIdx.x;
  double l0 = (double)bias[0], l1 = (double)bias[1];
  for (int c = 0; c < 128; ++c) {
    float v = fmaxf(S4[(size_t)c * PP + p] * scale[c] + shift[c], 0.f);
    l0 += (double)v * (double)W[c];
    l1 += (double)v * (double)W[128 + c];
  }
  int b = p >> 11, n = p & 2047;
  out[(size_t)b * OUTW + 2 * n] = (float)l0;
  out[(size_t)b * OUTW + 2 * n + 1] = (float)l1;
  mask[p] = (l0 < l1) ? 1 : 0;
}

// per-batch stable compaction + masked mean (fp64 sums)
__global__ __launch_bounds__(256) void compact_k(const int* __restrict__ mask,
                                                 const float* __restrict__ pc,
                                                 int* __restrict__ midx, int* __restrict__ cnt,
                                                 float* __restrict__ meanv) {
  int b = blockIdx.x, tid = threadIdx.x;
  __shared__ int sc[256];
  __shared__ int base;
  __shared__ double red[256];
  __shared__ double totals[3];
  if (tid == 0) base = 0;
  __syncthreads();
  double sx = 0.0, sy = 0.0, sz = 0.0;
  for (int n0 = 0; n0 < 2048; n0 += 256) {
    int n = n0 + tid;
    int mval = mask[b * 2048 + n];
    sc[tid] = mval;
    __syncthreads();
    for (int off = 1; off < 256; off <<= 1) {
      int v = (tid >= off) ? sc[tid - off] : 0;
      __syncthreads();
      sc[tid] += v;
      __syncthreads();
    }
    int excl = sc[tid] - mval;
    if (mval) {
      midx[b * 2048 + base + excl] = n;
      const float* q = &pc[((size_t)(b * 2048 + n)) * 4];
      sx += (double)q[0]; sy += (double)q[1]; sz += (double)q[2];
    }
    __syncthreads();
    if (tid == 0) base += sc[255];
    __syncthreads();
  }
  red[tid] = sx; __syncthreads();
  for (int off = 128; off; off >>= 1) { if (tid < off) red[tid] += red[tid + off]; __syncthreads(); }
  if (tid == 0) totals[0] = red[0];
  __syncthreads();
  red[tid] = sy; __syncthreads();
  for (int off = 128; off; off >>= 1) { if (tid < off) red[tid] += red[tid + off]; __syncthreads(); }
  if (tid == 0) totals[1] = red[0];
  __syncthreads();
  red[tid] = sz; __syncthreads();
  for (int off = 128; off; off >>= 1) { if (tid < off) red[tid] += red[tid + off]; __syncthreads(); }
  if (tid == 0) {
    totals[2] = red[0];
    int c = base;
    cnt[b] = c;
    double d = (double)(c > 1 ? c : 1);
    meanv[b * 3 + 0] = (float)(totals[0] / d);
    meanv[b * 3 + 1] = (float)(totals[1] / d);
    meanv[b * 3 + 2] = (float)(totals[2] / d);
  }
}

// --------------------------- threefry2x32 ----------------------------------
__device__ __forceinline__ uint32_t rotl32(uint32_t x, int r) {
  return (x << r) | (x >> (32 - r));
}
__device__ inline void threefry2x32(uint32_t k0, uint32_t k1, uint32_t& x0, uint32_t& x1) {
  const uint32_t ks[3] = {k0, k1, k0 ^ k1 ^ 0x1BD11BDAu};
  const int rot[2][4] = {{13, 15, 26, 6}, {17, 29, 16, 24}};
  x0 += ks[0]; x1 += ks[1];
  for (int i = 0; i < 5; ++i) {
    const int* r = rot[i & 1];
    for (int j = 0; j < 4; ++j) {
      x0 += x1; x1 = rotl32(x1, r[j]); x1 ^= x0;
    }
    x0 += ks[(i + 1) % 3];
    x1 += ks[(i + 2) % 3] + (uint32_t)(i + 1);
  }
}

// JAX partitionable threefry (default since 0.4.36): element e -> ctr (0,e),
// output word = w0 ^ w1.  (Verified: this fixed the 9-round box divergence.)
__global__ void sample_k(const float* __restrict__ pc, const int* __restrict__ midx,
                         const int* __restrict__ cnt, const float* __restrict__ meanv,
                         float* __restrict__ obj) {
  int e = blockIdx.x * 256 + threadIdx.x;
  if (e >= 16384) return;
  uint32_t x0 = 0u, x1 = (uint32_t)e;
  threefry2x32(0u, 42u, x0, x1);
  uint32_t bits = x0 ^ x1;
  float u = __uint_as_float((bits >> 9) | 0x3F800000u) - 1.0f;
  int b = e >> 9;
  int m = e & 511;
  int c_ = cnt[b];
  int pos = (int)(u * (float)c_);   // fp32 product + trunc, faithful to ref
  int cap = c_ - 1; if (cap < 0) cap = 0;
  if (pos > cap) pos = cap;
  float vx = 0.f, vy = 0.f, vz = 0.f;
  if (c_ > 0) {
    int n = midx[b * 2048 + pos];
    const float* q = &pc[((size_t)(b * 2048 + n)) * 4];
    vx = q[0] - meanv[b * 3 + 0];
    vy = q[1] - meanv[b * 3 + 1];
    vz = q[2] - meanv[b * 3 + 2];
  }
  int p2 = b * 512 + m;
  obj[p2] = vx;
  obj[PP2 + p2] = vy;
  obj[2 * PP2 + p2] = vz;
}

// FC: fp64 accumulation over fp32 data
__global__ void fc_gemm_k(const float* __restrict__ Xf, int ldx, int K,
                          const float* __restrict__ W, const float* __restrict__ bias,
                          const float* __restrict__ scale, const float* __restrict__ shift,
                          int relu, float* __restrict__ Y, int ldy, int yoff, int O) {
  int o = blockIdx.x * blockDim.x + threadIdx.x;
  int b = blockIdx.y;
  if (o >= O) return;
  const float* x = Xf + (size_t)b * ldx;
  const float* w = W + (size_t)o * K;
  double s = bias ? (double)bias[o] : 0.0;
  for (int k = 0; k < K; ++k) {
    float v = x[k];
    if (scale) {
      v = v * scale[k] + shift[k];
      if (relu) v = fmaxf(v, 0.f);
    }
    s += (double)v * (double)w[k];
  }
  Y[(size_t)b * ldy + yoff + o] = (float)s;
}

__global__ void fc_stats_k(const float* __restrict__ Y, int ldy, int O,
                           float* __restrict__ scale, float* __restrict__ shift) {
  int o = blockIdx.x * blockDim.x + threadIdx.x;
  if (o >= O) return;
  double s = 0.0, q = 0.0;
  for (int b = 0; b < 32; ++b) {
    double v = (double)Y[(size_t)b * ldy + o];
    s += v;
    q += v * v;
  }
  double m = s / 32.0;
  double v = q / 32.0 - m * m;
  if (v < 0.0) v = 0.0;
  double sc = 1.0 / sqrt(v + 1e-5);
  scale[o] = (float)sc;
  shift[o] = (float)(-m * sc);
}

__global__ void center_k(float* __restrict__ out, const float* __restrict__ cd,
                         const float* __restrict__ meanv) {
  int i = threadIdx.x;
  if (i >= 96) return;
  int b = i / 3, c = i - b * 3;
  out[(size_t)b * OUTW + 4155 + c] =
      out[(size_t)b * OUTW + 4096 + c] + cd[b * 3 + c] + meanv[b * 3 + c];
}

__global__ void size_fail_k(float* out, float code) {
  if (threadIdx.x == 0 && blockIdx.x == 0) out[0] = code;
}

// ---------------------------------------------------------------------------
extern "C" void kernel_launch(void* const* d_in, const int* in_sizes, int n_in, void* d_out,
                              int out_size, void* d_ws, size_t ws_size, hipStream_t stream) {
  float* out = (float*)d_out;
  static const int EXP[48] = {
      262144, 96, 256, 64, 4096, 64, 4096, 64, 8192, 128, 131072, 1024,
      558592, 512, 131072, 256, 32768, 128, 16384, 128, 256, 2,
      384, 128, 32768, 256, 131072, 512, 131840, 256, 32768, 128, 384, 3,
      384, 128, 16384, 128, 32768, 256, 131072, 512, 263680, 512, 131072, 256,
      15104, 59};
  if (n_in != 48) { size_fail_k<<<1, 1, 0, stream>>>(out, 9.0e6f + 99.0f * 1e4f); return; }
  if (out_size != 133056) { size_fail_k<<<1, 1, 0, stream>>>(out, 9.0e6f + 98.0f * 1e4f); return; }
  for (int i = 0; i < 48; ++i)
    if (in_sizes[i] != EXP[i]) {
      size_fail_k<<<1, 1, 0, stream>>>(out, 9.0e6f + (float)i * 1e4f);
      return;
    }
  if (ws_size < NEED_BYTES) { size_fail_k<<<1, 1, 0, stream>>>(out, 9.0e6f + 97.0f * 1e4f); return; }

  const float* pc = (const float*)d_in[0];
  const float* oh = (const float*)d_in[1];
#define IN(i) ((const float*)d_in[i])
  float* ws = (float*)d_ws;
  auto SC = [&](int s) { return ws + F_ST + (size_t)s * 2048; };
  auto SH = [&](int s) { return ws + F_ST + (size_t)s * 2048 + 1024; };
  enum { L_C1, L_C2, L_C3, L_C4, L_C5, L_S1, L_S2, L_S3, L_S4, L_T1, L_T2, L_T3,
         L_B1, L_B2, L_B3, L_B4, L_FT1, L_FT2, L_FB1, L_FB2 };

  float* Y1 = ws + F_Y1;
  float* Y2 = ws + F_Y2;
  float* Y3 = ws + F_Y3;
  float* Y4 = ws + F_Y4;
  double* P5s = (double*)(ws + F_P5S);
  double* P5q = (double*)(ws + F_P5Q);
  float*  P5m = ws + F_P5M;
  float* S1 = ws + F_S1;
  float* S2 = ws + F_S2;
  float* S3 = ws + F_S3;
  float* S4 = ws + F_S4;
  int* mask = (int*)(ws + F_MASK);
  int* midx = (int*)(ws + F_MIDX);
  int* cnt = (int*)(ws + F_CNT);
  float* meanv = ws + F_MEAN;
  float* gvec = ws + F_GVEC;
  float* gvt = ws + F_GVT;
  float* gvb = ws + F_GVB;
  float* gdot = ws + F_GDOT;
  float* obj = ws + F_OBJ;
  float* T1 = ws + F_T1;
  float* T2 = ws + F_T2;
  float* Bb1 = ws + F_B1;
  float* Bb2 = ws + F_B2;
  float* Bb3 = ws + F_B3;
  double* PTs = (double*)(ws + F_PT);
  double* PTq = (double*)(ws + F_PT + (size_t)2 * 256 * 512);
  float*  PTm = ws + F_PT + (size_t)4 * 256 * 512;
  double* PBs = (double*)(ws + F_PB);
  double* PBq = (double*)(ws + F_PB + (size_t)2 * 256 * 512);
  float*  PBm = ws + F_PB + (size_t)4 * 256 * 512;
  float* yt1 = ws + F_YT1;
  float* yt2 = ws + F_YT2;
  float* yb1 = ws + F_YB1;
  float* yb2 = ws + F_YB2;
  float* cd = ws + F_CD;

  dim3 blk(256);
  // ---- sf chain ----
  conv_pc_k<<<dim3(PP / 256, 64), blk, 0, stream>>>(pc, IN(2), IN(3), Y1);
  stats_k<<<64, blk, 0, stream>>>(Y1, PP, SC(L_C1), SH(L_C1));
  conv_gemm_k<false><<<dim3(1, PP / 64), blk, 0, stream>>>(Y1, PP, IN(4), 64, 64, IN(5),
      SC(L_C1), SH(L_C1), 1, nullptr, Y2, PP, nullptr, nullptr, nullptr, 0);
  stats_k<<<64, blk, 0, stream>>>(Y2, PP, SC(L_C2), SH(L_C2));
  conv_gemm_k<false><<<dim3(1, PP / 64), blk, 0, stream>>>(Y2, PP, IN(6), 64, 64, IN(7),
      SC(L_C2), SH(L_C2), 1, nullptr, Y3, PP, nullptr, nullptr, nullptr, 0);
  stats_k<<<64, blk, 0, stream>>>(Y3, PP, SC(L_C3), SH(L_C3));
  conv_gemm_k<false><<<dim3(2, PP / 64), blk, 0, stream>>>(Y3, PP, IN(8), 64, 64, IN(9),
      SC(L_C3), SH(L_C3), 1, nullptr, Y4, PP, nullptr, nullptr, nullptr, 0);
  stats_k<<<128, blk, 0, stream>>>(Y4, PP, SC(L_C4), SH(L_C4));
  conv_gemm_k<true><<<dim3(16, PP / 64), blk, 0, stream>>>(Y4, PP, IN(10), 128, 128, IN(11),
      SC(L_C4), SH(L_C4), 1, nullptr, nullptr, PP, P5s, P5q, P5m, 1024);
  stats_reduce_k<<<4, blk, 0, stream>>>(P5s, P5q, 1024, 1024, 1.0 / PP, SC(L_C5), SH(L_C5));
  onehot_k<<<1, 96, 0, stream>>>(oh, gvec, gvt, gvb);
  maxpool_g_k<<<(32 * 1024) / 256, blk, 0, stream>>>(P5m, 32, 1024, SC(L_C5), SH(L_C5), 0,
                                                     gvec, 1027, 3);
  gdot_k<<<64, blk, 0, stream>>>(IN(12), gvec, gdot);
  // ---- seg head ----
  conv_gemm_k<false><<<dim3(8, PP / 64), blk, 0, stream>>>(Y2, PP, IN(12) + 1027, 1091, 64,
      IN(13), SC(L_C2), SH(L_C2), 1, gdot, S1, PP, nullptr, nullptr, nullptr, 0);
  stats_k<<<512, blk, 0, stream>>>(S1, PP, SC(L_S1), SH(L_S1));
  conv_gemm_k<false><<<dim3(4, PP / 64), blk, 0, stream>>>(S1, PP, IN(14), 512, 512, IN(15),
      SC(L_S1), SH(L_S1), 1, nullptr, S2, PP, nullptr, nullptr, nullptr, 0);
  stats_k<<<256, blk, 0, stream>>>(S2, PP, SC(L_S2), SH(L_S2));
  conv_gemm_k<false><<<dim3(2, PP / 64), blk, 0, stream>>>(S2, PP, IN(16), 256, 256, IN(17),
      SC(L_S2), SH(L_S2), 1, nullptr, S3, PP, nullptr, nullptr, nullptr, 0);
  stats_k<<<128, blk, 0, stream>>>(S3, PP, SC(L_S3), SH(L_S3));
  conv_gemm_k<false><<<dim3(2, PP / 64), blk, 0, stream>>>(S3, PP, IN(18), 128, 128, IN(19),
      SC(L_S3), SH(L_S3), 1, nullptr, S4, PP, nullptr, nullptr, nullptr, 0);
  stats_k<<<128, blk, 0, stream>>>(S4, PP, SC(L_S4), SH(L_S4));
  logits_k<<<PP / 256, blk, 0, stream>>>(S4, IN(20), IN(21), SC(L_S4), SH(L_S4), out, mask);
  compact_k<<<32, blk, 0, stream>>>(mask, pc, midx, cnt, meanv);
  sample_k<<<64, blk, 0, stream>>>(pc, midx, cnt, meanv, obj);
  // ---- t-net ----
  conv_k3_k<<<dim3(PP2 / 256, 128), blk, 0, stream>>>(obj, IN(22), IN(23), nullptr, T1);
  stats_k<<<128, blk, 0, stream>>>(T1, PP2, SC(L_T1), SH(L_T1));
  conv_gemm_k<false><<<dim3(4, PP2 / 64), blk, 0, stream>>>(T1, PP2, IN(24), 128, 128, IN(25),
      SC(L_T1), SH(L_T1), 1, nullptr, T2, PP2, nullptr, nullptr, nullptr, 0);
  stats_k<<<256, blk, 0, stream>>>(T2, PP2, SC(L_T2), SH(L_T2));
  conv_gemm_k<true><<<dim3(8, PP2 / 64), blk, 0, stream>>>(T2, PP2, IN(26), 256, 256, IN(27),
      SC(L_T2), SH(L_T2), 1, nullptr, nullptr, PP2, PTs, PTq, PTm, 512);
  stats_reduce_k<<<2, blk, 0, stream>>>(PTs, PTq, 256, 512, 1.0 / PP2, SC(L_T3), SH(L_T3));
  maxpool_g_k<<<(32 * 512) / 256, blk, 0, stream>>>(PTm, 8, 512, SC(L_T3), SH(L_T3), 1, gvt,
                                                    515, 3);
  fc_gemm_k<<<dim3(1, 32), blk, 0, stream>>>(gvt, 515, 515, IN(28), IN(29), nullptr, nullptr,
                                             0, yt1, 256, 0, 256);
  fc_stats_k<<<1, blk, 0, stream>>>(yt1, 256, 256, SC(L_FT1), SH(L_FT1));
  fc_gemm_k<<<dim3(1, 32), blk, 0, stream>>>(yt1, 256, 256, IN(30), IN(31), SC(L_FT1),
                                             SH(L_FT1), 1, yt2, 128, 0, 128);
  fc_stats_k<<<1, blk, 0, stream>>>(yt2, 128, 128, SC(L_FT2), SH(L_FT2));
  fc_gemm_k<<<dim3(1, 32), blk, 0, stream>>>(yt2, 128, 128, IN(32), IN(33), SC(L_FT2),
                                             SH(L_FT2), 1, cd, 3, 0, 3);
  // ---- box net ----
  conv_k3_k<<<dim3(PP2 / 256, 128), blk, 0, stream>>>(obj, IN(34), IN(35), cd, Bb1);
  stats_k<<<128, blk, 0, stream>>>(Bb1, PP2, SC(L_B1), SH(L_B1));
  conv_gemm_k<false><<<dim3(2, PP2 / 64), blk, 0, stream>>>(Bb1, PP2, IN(36), 128, 128, IN(37),
      SC(L_B1), SH(L_B1), 1, nullptr, Bb2, PP2, nullptr, nullptr, nullptr, 0);
  stats_k<<<128, blk, 0, stream>>>(Bb2, PP2, SC(L_B2), SH(L_B2));
  conv_gemm_k<false><<<dim3(4, PP2 / 64), blk, 0, stream>>>(Bb2, PP2, IN(38), 128, 128, IN(39),
      SC(L_B2), SH(L_B2), 1, nullptr, Bb3, PP2, nullptr, nullptr, nullptr, 0);
  stats_k<<<256, blk, 0, stream>>>(Bb3, PP2, SC(L_B3), SH(L_B3));
  conv_gemm_k<true><<<dim3(8, PP2 / 64), blk, 0, stream>>>(Bb3, PP2, IN(40), 256, 256, IN(41),
      SC(L_B3), SH(L_B3), 1, nullptr, nullptr, PP2, PBs, PBq, PBm, 512);
  stats_reduce_k<<<2, blk, 0, stream>>>(PBs, PBq, 256, 512, 1.0 / PP2, SC(L_B4), SH(L_B4));
  maxpool_g_k<<<(32 * 512) / 256, blk, 0, stream>>>(PBm, 8, 512, SC(L_B4), SH(L_B4), 1, gvb,
                                                    515, 0);
  fc_gemm_k<<<dim3(2, 32), blk, 0, stream>>>(gvb, 515, 515, IN(42), IN(43), nullptr, nullptr,
                                             0, yb1, 512, 0, 512);
  fc_stats_k<<<2, blk, 0, stream>>>(yb1, 512, 512, SC(L_FB1), SH(L_FB1));
  fc_gemm_k<<<dim3(1, 32), blk, 0, stream>>>(yb1, 512, 512, IN(44), IN(45), SC(L_FB1),
                                             SH(L_FB1), 1, yb2, 256, 0, 256);
  fc_stats_k<<<1, blk, 0, stream>>>(yb2, 256, 256, SC(L_FB2), SH(L_FB2));
  fc_gemm_k<<<dim3(1, 32), blk, 0, stream>>>(yb2, 256, 256, IN(46), IN(47), SC(L_FB2),
                                             SH(L_FB2), 1, out, OUTW, 4096, 59);
  center_k<<<1, 96, 0, stream>>>(out, cd, meanv);
#undef IN
}

// Round 12
// 2416.872 us; speedup vs baseline: 2.3145x; 1.2358x over previous
//
#include <hip/hip_runtime.h>
#include <cstdint>

// ---------------------------------------------------------------------------
// Frustum-PointNet forward, MI355X.  R12 = R11 + 128x128-tile fp32 GEMM
// (8x8 acc/thread, float4 LDS both operands, transposed weight tile) for all
// layers with O>=128.  conv2/conv3 (O=64) keep the 64x64 kernel.
// Accumulation order per output element unchanged => mask bits identical.
// ---------------------------------------------------------------------------

constexpr int PP   = 65536;   // B*N
constexpr int PP2  = 16384;   // B*M
constexpr int OUTW = 4158;    // 2*N + 59 + 3

// ---- big-buffer layout (float offsets), liveness-overlapped ----
constexpr size_t F_Y1 = 0;                       // 64*PP
constexpr size_t F_Y2 = (size_t)64 * PP;         // 64*PP (pointfeat; live till S1)
constexpr size_t F_Y3 = (size_t)128 * PP;        // 64*PP
constexpr size_t F_Y4 = (size_t)192 * PP;        // 128*PP
// conv5 fused partials (now 512 tiles x 1024 ch): doubles fill Y1 slot.
constexpr size_t F_P5S = 0;                          // double[512*1024]
constexpr size_t F_P5Q = (size_t)2 * 1024 * 1024;    // double[512*1024]
constexpr size_t F_P5M = (size_t)128 * PP;           // float[512*1024] in dead Y3 slot
static_assert(F_P5Q + 2 * 1024 * 1024 <= F_Y2, "P5 partials exceed Y1 slot");
static_assert(F_P5M + 1024 * 1024 <= (size_t)192 * PP, "P5m exceeds Y3 slot");
constexpr size_t F_S1 = (size_t)320 * PP;        // 512*PP
constexpr size_t F_S2 = 0;                       // 256*PP
constexpr size_t F_S3 = (size_t)320 * PP;        // 128*PP
constexpr size_t F_S4 = (size_t)448 * PP;        // 128*PP
// t/b overlay in [0, 256*PP):
constexpr size_t F_T1 = 0;                                  // 128*PP2
constexpr size_t F_T2 = F_T1 + (size_t)128 * PP2;           // 256*PP2
constexpr size_t F_PT = F_T2 + (size_t)256 * PP2;           // 5*256*512 slot
constexpr size_t F_B1 = F_PT + (size_t)5 * 256 * 512;       // 128*PP2
constexpr size_t F_B2 = F_B1 + (size_t)128 * PP2;           // 128*PP2
constexpr size_t F_B3 = F_B2 + (size_t)128 * PP2;           // 256*PP2
constexpr size_t F_PB = F_B3 + (size_t)256 * PP2;           // 5*256*512 slot
static_assert(F_PB + (size_t)5 * 256 * 512 <= (size_t)256 * PP, "t/b overlay overflow");
static_assert((F_PT % 2) == 0 && (F_PB % 2) == 0, "double alignment");

// ---- persistent small region at 832*PP ----
constexpr size_t SB       = (size_t)832 * PP;
constexpr size_t F_MASK   = SB;                    // int[PP]
constexpr size_t F_MIDX   = F_MASK + PP;           // int[PP]
constexpr size_t F_CNT    = F_MIDX + PP;           // int[32]
constexpr size_t F_MEAN   = F_CNT + 32;            // float[96]
constexpr size_t F_GVEC   = F_MEAN + 96;           // 32*1027
constexpr size_t F_GVT    = F_GVEC + 32 * 1027;    // 32*515
constexpr size_t F_GVB    = F_GVT + 32 * 515;      // 32*515
constexpr size_t F_GDOT   = F_GVB + 32 * 515;      // 512*32
constexpr size_t F_YT1    = F_GDOT + 512 * 32;     // 32*256
constexpr size_t F_YT2    = F_YT1 + 32 * 256;      // 32*128
constexpr size_t F_YB1    = F_YT2 + 32 * 128;      // 32*512
constexpr size_t F_YB2    = F_YB1 + 32 * 512;      // 32*256
constexpr size_t F_CD     = F_YB2 + 32 * 256;      // 96
constexpr size_t F_OBJ    = F_CD + 96;             // 3*PP2
constexpr size_t F_ST     = F_OBJ + (size_t)3 * PP2;  // 20 slots * 2048 floats
constexpr size_t F_END    = F_ST + 20 * 2048;
constexpr size_t NEED_BYTES = F_END * 4;           // ~219.7 MB

#define NEG_INF (-3.402823466e38f)

// ---------------------------------------------------------------------------
__global__ __launch_bounds__(256) void conv_pc_k(const float* __restrict__ pc,
                                                 const float* __restrict__ W,
                                                 const float* __restrict__ bias,
                                                 float* __restrict__ Y) {
  int p = blockIdx.x * 256 + threadIdx.x;
  int o = blockIdx.y;
  float4 v = *reinterpret_cast<const float4*>(&pc[(size_t)p * 4]);
  float s = bias[o] + v.x * W[o * 4 + 0] + v.y * W[o * 4 + 1] + v.z * W[o * 4 + 2] +
            v.w * W[o * 4 + 3];
  Y[(size_t)o * PP + p] = s;
}

__global__ __launch_bounds__(256) void conv_k3_k(const float* __restrict__ Xc,
                                                 const float* __restrict__ W,
                                                 const float* __restrict__ bias,
                                                 const float* __restrict__ cd,
                                                 float* __restrict__ Y) {
  int p = blockIdx.x * 256 + threadIdx.x;
  int o = blockIdx.y;
  int b = p >> 9;  // M=512
  float x0 = Xc[p], x1 = Xc[PP2 + p], x2 = Xc[2 * PP2 + p];
  if (cd) { x0 -= cd[b * 3]; x1 -= cd[b * 3 + 1]; x2 -= cd[b * 3 + 2]; }
  Y[(size_t)o * PP2 + p] = bias[o] + x0 * W[o * 3] + x1 * W[o * 3 + 1] + x2 * W[o * 3 + 2];
}

// ---------------------------------------------------------------------------
// 64x64-tile fp32 GEMM (kept for O=64 layers conv2/conv3).
__global__ __launch_bounds__(256) void conv_gemm_k(
    const float* __restrict__ X, int ldx, const float* __restrict__ W, int ldw, int C,
    const float* __restrict__ bias, const float* __restrict__ scale,
    const float* __restrict__ shift, int relu_in, float* __restrict__ Y, int Ptot) {
  __shared__ float Xs[16][64];
  __shared__ float Ws[64][17];
  const int tid = threadIdx.x;
  const int tx = tid & 15, ty = tid >> 4;
  const int o0 = blockIdx.x * 64, p0 = blockIdx.y * 64;
  float acc[4][4] = {};
  for (int c0 = 0; c0 < C; c0 += 16) {
#pragma unroll
    for (int j = 0; j < 4; ++j) {
      int idx = tid + j * 256;
      int k = idx >> 6, n = idx & 63;
      int c = c0 + k;
      float v = X[(size_t)c * ldx + p0 + n];
      if (scale) v = v * scale[c] + shift[c];
      if (relu_in) v = fmaxf(v, 0.f);
      Xs[k][n] = v;
    }
#pragma unroll
    for (int j = 0; j < 4; ++j) {
      int idx = tid + j * 256;
      int o = idx >> 4, k = idx & 15;
      Ws[o][k] = W[(size_t)(o0 + o) * ldw + c0 + k];
    }
    __syncthreads();
#pragma unroll
    for (int k = 0; k < 16; ++k) {
      float bx[4], aw[4];
#pragma unroll
      for (int j = 0; j < 4; ++j) bx[j] = Xs[k][tx * 4 + j];
#pragma unroll
      for (int i = 0; i < 4; ++i) aw[i] = Ws[ty * 4 + i][k];
#pragma unroll
      for (int i = 0; i < 4; ++i)
#pragma unroll
        for (int j = 0; j < 4; ++j) acc[i][j] = fmaf(aw[i], bx[j], acc[i][j]);
    }
    __syncthreads();
  }
#pragma unroll
  for (int i = 0; i < 4; ++i) {
    int o = o0 + ty * 4 + i;
    float badd = bias[o];
#pragma unroll
    for (int j = 0; j < 4; ++j) acc[i][j] += badd;
  }
#pragma unroll
  for (int i = 0; i < 4; ++i) {
    int o = o0 + ty * 4 + i;
    float4 v = make_float4(acc[i][0], acc[i][1], acc[i][2], acc[i][3]);
    *reinterpret_cast<float4*>(&Y[(size_t)o * Ptot + p0 + tx * 4]) = v;
  }
}

// ---------------------------------------------------------------------------
// 128x128-tile fp32 GEMM, 8x8 acc/thread, float4 LDS reads both operands.
// Requires C % 16 == 0, O % 128 == 0, P % 128 == 0 (all our layers comply).
// FUSED: per-p-tile fp64 sum/sumsq + fp32 max per channel (no Y store).
template <bool FUSED>
__global__ __launch_bounds__(256) void gemm_big_k(
    const float* __restrict__ X, int ldx, const float* __restrict__ W, int ldw, int C,
    const float* __restrict__ bias, const float* __restrict__ scale,
    const float* __restrict__ shift, int relu_in, const float* __restrict__ gadd,
    float* __restrict__ Y, int Ptot, double* __restrict__ psum, double* __restrict__ psq,
    float* __restrict__ pmax, int Ototal) {
  __shared__ float Xs[16][128];
  __shared__ float Wt[16][128];
  const int tid = threadIdx.x;
  const int tx = tid & 15, ty = tid >> 4;
  const int o0 = blockIdx.x * 128, p0 = blockIdx.y * 128;
  float acc[8][8] = {};
  for (int c0 = 0; c0 < C; c0 += 16) {
    // stage X (float4, with folded BN+relu of the previous layer)
#pragma unroll
    for (int q = 0; q < 2; ++q) {
      int f = tid + q * 256;           // float4 index in [0,512)
      int k = f >> 5, c4 = f & 31;
      int c = c0 + k;
      float4 v = *reinterpret_cast<const float4*>(&X[(size_t)c * ldx + p0 + c4 * 4]);
      if (scale) {
        float sc = scale[c], sh = shift[c];
        v.x = v.x * sc + sh; v.y = v.y * sc + sh;
        v.z = v.z * sc + sh; v.w = v.w * sc + sh;
      }
      if (relu_in) {
        v.x = fmaxf(v.x, 0.f); v.y = fmaxf(v.y, 0.f);
        v.z = fmaxf(v.z, 0.f); v.w = fmaxf(v.w, 0.f);
      }
      *reinterpret_cast<float4*>(&Xs[k][c4 * 4]) = v;
    }
    // stage W transposed: Wt[k][o] = W[o0+o][c0+k]
#pragma unroll
    for (int q = 0; q < 8; ++q) {
      int idx = tid + q * 256;
      int k = idx >> 7, o = idx & 127;
      Wt[k][o] = W[(size_t)(o0 + o) * ldw + c0 + k];
    }
    __syncthreads();
#pragma unroll
    for (int k = 0; k < 16; ++k) {
      float bx[8], aw[8];
      *reinterpret_cast<float4*>(&bx[0]) = *reinterpret_cast<const float4*>(&Xs[k][tx * 8]);
      *reinterpret_cast<float4*>(&bx[4]) = *reinterpret_cast<const float4*>(&Xs[k][tx * 8 + 4]);
      *reinterpret_cast<float4*>(&aw[0]) = *reinterpret_cast<const float4*>(&Wt[k][ty * 8]);
      *reinterpret_cast<float4*>(&aw[4]) = *reinterpret_cast<const float4*>(&Wt[k][ty * 8 + 4]);
#pragma unroll
      for (int i = 0; i < 8; ++i)
#pragma unroll
        for (int j = 0; j < 8; ++j) acc[i][j] = fmaf(aw[i], bx[j], acc[i][j]);
    }
    __syncthreads();
  }
#pragma unroll
  for (int i = 0; i < 8; ++i) {
    int o = o0 + ty * 8 + i;
    float badd = bias ? bias[o] : 0.f;
    if (gadd) badd += gadd[o * 32 + (p0 >> 11)];  // batch constant across 128-tile
#pragma unroll
    for (int j = 0; j < 8; ++j) acc[i][j] += badd;
  }
  if constexpr (!FUSED) {
#pragma unroll
    for (int i = 0; i < 8; ++i) {
      int o = o0 + ty * 8 + i;
      float* dst = &Y[(size_t)o * Ptot + p0 + tx * 8];
      *reinterpret_cast<float4*>(dst) =
          make_float4(acc[i][0], acc[i][1], acc[i][2], acc[i][3]);
      *reinterpret_cast<float4*>(dst + 4) =
          make_float4(acc[i][4], acc[i][5], acc[i][6], acc[i][7]);
    }
  } else {
    __shared__ double redd[16][128];
    // sum (fp64)
#pragma unroll
    for (int i = 0; i < 8; ++i) {
      double s = 0.0;
#pragma unroll
      for (int j = 0; j < 8; ++j) s += (double)acc[i][j];
      redd[tx][ty * 8 + i] = s;
    }
    __syncthreads();
    if (tid < 128) {
      double s = 0.0;
      for (int t = 0; t < 16; ++t) s += redd[t][tid];
      psum[(size_t)blockIdx.y * Ototal + o0 + tid] = s;
    }
    __syncthreads();
    // sumsq (fp64)
#pragma unroll
    for (int i = 0; i < 8; ++i) {
      double s = 0.0;
#pragma unroll
      for (int j = 0; j < 8; ++j) s += (double)acc[i][j] * (double)acc[i][j];
      redd[tx][ty * 8 + i] = s;
    }
    __syncthreads();
    if (tid < 128) {
      double s = 0.0;
      for (int t = 0; t < 16; ++t) s += redd[t][tid];
      psq[(size_t)blockIdx.y * Ototal + o0 + tid] = s;
    }
    __syncthreads();
    // max
#pragma unroll
    for (int i = 0; i < 8; ++i) {
      float mx = acc[i][0];
#pragma unroll
      for (int j = 1; j < 8; ++j) mx = fmaxf(mx, acc[i][j]);
      redd[tx][ty * 8 + i] = (double)mx;
    }
    __syncthreads();
    if (tid < 128) {
      double s = -1.0e300;
      for (int t = 0; t < 16; ++t) s = s > redd[t][tid] ? s : redd[t][tid];
      pmax[(size_t)blockIdx.y * Ototal + o0 + tid] = (float)s;
    }
  }
}

// BN stats over stored (O x Ptot) fp32 activation; fp64 accumulation.
__global__ __launch_bounds__(256) void stats_k(const float* __restrict__ Y, int Ptot,
                                               float* __restrict__ scale,
                                               float* __restrict__ shift) {
  int o = blockIdx.x;
  const float* row = Y + (size_t)o * Ptot;
  double s = 0.0, q = 0.0;
  for (int p = threadIdx.x; p < Ptot; p += 256) {
    double v = (double)row[p];
    s += v;
    q += v * v;
  }
  __shared__ double ss[256], qq[256];
  int tid = threadIdx.x;
  ss[tid] = s; qq[tid] = q;
  __syncthreads();
  for (int off = 128; off; off >>= 1) {
    if (tid < off) { ss[tid] += ss[tid + off]; qq[tid] += qq[tid + off]; }
    __syncthreads();
  }
  if (tid == 0) {
    double m = ss[0] / (double)Ptot;
    double v = qq[0] / (double)Ptot - m * m;
    if (v < 0.0) v = 0.0;
    double sc = 1.0 / sqrt(v + 1e-5);
    scale[o] = (float)sc;
    shift[o] = (float)(-m * sc);
  }
}

__global__ void stats_reduce_k(const double* __restrict__ psum, const double* __restrict__ psq,
                               int ntiles, int O, double invP, float* __restrict__ scale,
                               float* __restrict__ shift) {
  int o = blockIdx.x * blockDim.x + threadIdx.x;
  if (o >= O) return;
  double s = 0.0, q = 0.0;
  for (int t = 0; t < ntiles; ++t) {
    s += psum[(size_t)t * O + o];
    q += psq[(size_t)t * O + o];
  }
  double m = s * invP;
  double v = q * invP - m * m;
  if (v < 0.0) v = 0.0;
  double sc = 1.0 / sqrt(v + 1e-5);
  scale[o] = (float)sc;
  shift[o] = (float)(-m * sc);
}

__global__ void maxpool_g_k(const float* __restrict__ pmax, int tilesPB, int O,
                            const float* __restrict__ scale, const float* __restrict__ shift,
                            int relu, float* __restrict__ out, int ostride, int ooff) {
  int idx = blockIdx.x * blockDim.x + threadIdx.x;
  if (idx >= 32 * O) return;
  int b = idx / O, o = idx - b * O;
  float m = NEG_INF;
  for (int t = b * tilesPB; t < (b + 1) * tilesPB; ++t) m = fmaxf(m, pmax[(size_t)t * O + o]);
  float v = scale[o] * m + shift[o];
  if (relu) v = fmaxf(v, 0.f);
  out[(size_t)b * ostride + ooff + o] = v;
}

__global__ void onehot_k(const float* __restrict__ oh, float* __restrict__ gvec,
                         float* __restrict__ gvt, float* __restrict__ gvb) {
  int i = threadIdx.x;
  if (i >= 96) return;
  int b = i / 3, c = i - b * 3;
  float v = oh[b * 3 + c];
  gvec[b * 1027 + c] = v;
  gvt[b * 515 + c] = v;
  gvb[b * 515 + 512 + c] = v;
}

__global__ void gdot_k(const float* __restrict__ W, const float* __restrict__ gvec,
                       float* __restrict__ gdot) {
  int idx = blockIdx.x * 256 + threadIdx.x;  // 512*32
  int o = idx >> 5, b = idx & 31;
  double s = 0.0;
  const float* wr = W + (size_t)o * 1091;
  const float* gr = gvec + (size_t)b * 1027;
  for (int c = 0; c < 1027; ++c) s += (double)wr[c] * (double)gr[c];
  gdot[o * 32 + b] = (float)s;
}

__global__ __launch_bounds__(256) void logits_k(const float* __restrict__ S4,
                                                const float* __restrict__ W,
                                                const float* __restrict__ bias,
                                                const float* __restrict__ scale,
                                                const float* __restrict__ shift,
                                                float* __restrict__ out,
                                                int* __restrict__ mask) {
  int p = blockIdx.x * 256 + threadIdx.x;
  double l0 = (double)bias[0], l1 = (double)bias[1];
  for (int c = 0; c < 128; ++c) {
    float v = fmaxf(S4[(size_t)c * PP + p] * scale[c] + shift[c], 0.f);
    l0 += (double)v * (double)W[c];
    l1 += (double)v * (double)W[128 + c];
  }
  int b = p >> 11, n = p & 2047;
  out[(size_t)b * OUTW + 2 * n] = (float)l0;
  out[(size_t)b * OUTW + 2 * n + 1] = (float)l1;
  mask[p] = (l0 < l1) ? 1 : 0;
}

__global__ __launch_bounds__(256) void compact_k(const int* __restrict__ mask,
                                                 const float* __restrict__ pc,
                                                 int* __restrict__ midx, int* __restrict__ cnt,
                                                 float* __restrict__ meanv) {
  int b = blockIdx.x, tid = threadIdx.x;
  __shared__ int sc[256];
  __shared__ int base;
  __shared__ double red[256];
  __shared__ double totals[3];
  if (tid == 0) base = 0;
  __syncthreads();
  double sx = 0.0, sy = 0.0, sz = 0.0;
  for (int n0 = 0; n0 < 2048; n0 += 256) {
    int n = n0 + tid;
    int mval = mask[b * 2048 + n];
    sc[tid] = mval;
    __syncthreads();
    for (int off = 1; off < 256; off <<= 1) {
      int v = (tid >= off) ? sc[tid - off] : 0;
      __syncthreads();
      sc[tid] += v;
      __syncthreads();
    }
    int excl = sc[tid] - mval;
    if (mval) {
      midx[b * 2048 + base + excl] = n;
      const float* q = &pc[((size_t)(b * 2048 + n)) * 4];
      sx += (double)q[0]; sy += (double)q[1]; sz += (double)q[2];
    }
    __syncthreads();
    if (tid == 0) base += sc[255];
    __syncthreads();
  }
  red[tid] = sx; __syncthreads();
  for (int off = 128; off; off >>= 1) { if (tid < off) red[tid] += red[tid + off]; __syncthreads(); }
  if (tid == 0) totals[0] = red[0];
  __syncthreads();
  red[tid] = sy; __syncthreads();
  for (int off = 128; off; off >>= 1) { if (tid < off) red[tid] += red[tid + off]; __syncthreads(); }
  if (tid == 0) totals[1] = red[0];
  __syncthreads();
  red[tid] = sz; __syncthreads();
  for (int off = 128; off; off >>= 1) { if (tid < off) red[tid] += red[tid + off]; __syncthreads(); }
  if (tid == 0) {
    totals[2] = red[0];
    int c = base;
    cnt[b] = c;
    double d = (double)(c > 1 ? c : 1);
    meanv[b * 3 + 0] = (float)(totals[0] / d);
    meanv[b * 3 + 1] = (float)(totals[1] / d);
    meanv[b * 3 + 2] = (float)(totals[2] / d);
  }
}

// --------------------------- threefry2x32 ----------------------------------
__device__ __forceinline__ uint32_t rotl32(uint32_t x, int r) {
  return (x << r) | (x >> (32 - r));
}
__device__ inline void threefry2x32(uint32_t k0, uint32_t k1, uint32_t& x0, uint32_t& x1) {
  const uint32_t ks[3] = {k0, k1, k0 ^ k1 ^ 0x1BD11BDAu};
  const int rot[2][4] = {{13, 15, 26, 6}, {17, 29, 16, 24}};
  x0 += ks[0]; x1 += ks[1];
  for (int i = 0; i < 5; ++i) {
    const int* r = rot[i & 1];
    for (int j = 0; j < 4; ++j) {
      x0 += x1; x1 = rotl32(x1, r[j]); x1 ^= x0;
    }
    x0 += ks[(i + 1) % 3];
    x1 += ks[(i + 2) % 3] + (uint32_t)(i + 1);
  }
}

// JAX partitionable threefry (default since 0.4.36): ctr (0,e), bits = w0^w1.
__global__ void sample_k(const float* __restrict__ pc, const int* __restrict__ midx,
                         const int* __restrict__ cnt, const float* __restrict__ meanv,
                         float* __restrict__ obj) {
  int e = blockIdx.x * 256 + threadIdx.x;
  if (e >= 16384) return;
  uint32_t x0 = 0u, x1 = (uint32_t)e;
  threefry2x32(0u, 42u, x0, x1);
  uint32_t bits = x0 ^ x1;
  float u = __uint_as_float((bits >> 9) | 0x3F800000u) - 1.0f;
  int b = e >> 9;
  int m = e & 511;
  int c_ = cnt[b];
  int pos = (int)(u * (float)c_);
  int cap = c_ - 1; if (cap < 0) cap = 0;
  if (pos > cap) pos = cap;
  float vx = 0.f, vy = 0.f, vz = 0.f;
  if (c_ > 0) {
    int n = midx[b * 2048 + pos];
    const float* q = &pc[((size_t)(b * 2048 + n)) * 4];
    vx = q[0] - meanv[b * 3 + 0];
    vy = q[1] - meanv[b * 3 + 1];
    vz = q[2] - meanv[b * 3 + 2];
  }
  int p2 = b * 512 + m;
  obj[p2] = vx;
  obj[PP2 + p2] = vy;
  obj[2 * PP2 + p2] = vz;
}

__global__ void fc_gemm_k(const float* __restrict__ Xf, int ldx, int K,
                          const float* __restrict__ W, const float* __restrict__ bias,
                          const float* __restrict__ scale, const float* __restrict__ shift,
                          int relu, float* __restrict__ Y, int ldy, int yoff, int O) {
  int o = blockIdx.x * blockDim.x + threadIdx.x;
  int b = blockIdx.y;
  if (o >= O) return;
  const float* x = Xf + (size_t)b * ldx;
  const float* w = W + (size_t)o * K;
  double s = bias ? (double)bias[o] : 0.0;
  for (int k = 0; k < K; ++k) {
    float v = x[k];
    if (scale) {
      v = v * scale[k] + shift[k];
      if (relu) v = fmaxf(v, 0.f);
    }
    s += (double)v * (double)w[k];
  }
  Y[(size_t)b * ldy + yoff + o] = (float)s;
}

__global__ void fc_stats_k(const float* __restrict__ Y, int ldy, int O,
                           float* __restrict__ scale, float* __restrict__ shift) {
  int o = blockIdx.x * blockDim.x + threadIdx.x;
  if (o >= O) return;
  double s = 0.0, q = 0.0;
  for (int b = 0; b < 32; ++b) {
    double v = (double)Y[(size_t)b * ldy + o];
    s += v;
    q += v * v;
  }
  double m = s / 32.0;
  double v = q / 32.0 - m * m;
  if (v < 0.0) v = 0.0;
  double sc = 1.0 / sqrt(v + 1e-5);
  scale[o] = (float)sc;
  shift[o] = (float)(-m * sc);
}

__global__ void center_k(float* __restrict__ out, const float* __restrict__ cd,
                         const float* __restrict__ meanv) {
  int i = threadIdx.x;
  if (i >= 96) return;
  int b = i / 3, c = i - b * 3;
  out[(size_t)b * OUTW + 4155 + c] =
      out[(size_t)b * OUTW + 4096 + c] + cd[b * 3 + c] + meanv[b * 3 + c];
}

__global__ void size_fail_k(float* out, float code) {
  if (threadIdx.x == 0 && blockIdx.x == 0) out[0] = code;
}

// ---------------------------------------------------------------------------
extern "C" void kernel_launch(void* const* d_in, const int* in_sizes, int n_in, void* d_out,
                              int out_size, void* d_ws, size_t ws_size, hipStream_t stream) {
  float* out = (float*)d_out;
  static const int EXP[48] = {
      262144, 96, 256, 64, 4096, 64, 4096, 64, 8192, 128, 131072, 1024,
      558592, 512, 131072, 256, 32768, 128, 16384, 128, 256, 2,
      384, 128, 32768, 256, 131072, 512, 131840, 256, 32768, 128, 384, 3,
      384, 128, 16384, 128, 32768, 256, 131072, 512, 263680, 512, 131072, 256,
      15104, 59};
  if (n_in != 48) { size_fail_k<<<1, 1, 0, stream>>>(out, 9.0e6f + 99.0f * 1e4f); return; }
  if (out_size != 133056) { size_fail_k<<<1, 1, 0, stream>>>(out, 9.0e6f + 98.0f * 1e4f); return; }
  for (int i = 0; i < 48; ++i)
    if (in_sizes[i] != EXP[i]) {
      size_fail_k<<<1, 1, 0, stream>>>(out, 9.0e6f + (float)i * 1e4f);
      return;
    }
  if (ws_size < NEED_BYTES) { size_fail_k<<<1, 1, 0, stream>>>(out, 9.0e6f + 97.0f * 1e4f); return; }

  const float* pc = (const float*)d_in[0];
  const float* oh = (const float*)d_in[1];
#define IN(i) ((const float*)d_in[i])
  float* ws = (float*)d_ws;
  auto SC = [&](int s) { return ws + F_ST + (size_t)s * 2048; };
  auto SH = [&](int s) { return ws + F_ST + (size_t)s * 2048 + 1024; };
  enum { L_C1, L_C2, L_C3, L_C4, L_C5, L_S1, L_S2, L_S3, L_S4, L_T1, L_T2, L_T3,
         L_B1, L_B2, L_B3, L_B4, L_FT1, L_FT2, L_FB1, L_FB2 };

  float* Y1 = ws + F_Y1;
  float* Y2 = ws + F_Y2;
  float* Y3 = ws + F_Y3;
  float* Y4 = ws + F_Y4;
  double* P5s = (double*)(ws + F_P5S);
  double* P5q = (double*)(ws + F_P5Q);
  float*  P5m = ws + F_P5M;
  float* S1 = ws + F_S1;
  float* S2 = ws + F_S2;
  float* S3 = ws + F_S3;
  float* S4 = ws + F_S4;
  int* mask = (int*)(ws + F_MASK);
  int* midx = (int*)(ws + F_MIDX);
  int* cnt = (int*)(ws + F_CNT);
  float* meanv = ws + F_MEAN;
  float* gvec = ws + F_GVEC;
  float* gvt = ws + F_GVT;
  float* gvb = ws + F_GVB;
  float* gdot = ws + F_GDOT;
  float* obj = ws + F_OBJ;
  float* T1 = ws + F_T1;
  float* T2 = ws + F_T2;
  float* Bb1 = ws + F_B1;
  float* Bb2 = ws + F_B2;
  float* Bb3 = ws + F_B3;
  double* PTs = (double*)(ws + F_PT);
  double* PTq = (double*)(ws + F_PT + (size_t)2 * 256 * 512);
  float*  PTm = ws + F_PT + (size_t)4 * 256 * 512;
  double* PBs = (double*)(ws + F_PB);
  double* PBq = (double*)(ws + F_PB + (size_t)2 * 256 * 512);
  float*  PBm = ws + F_PB + (size_t)4 * 256 * 512;
  float* yt1 = ws + F_YT1;
  float* yt2 = ws + F_YT2;
  float* yb1 = ws + F_YB1;
  float* yb2 = ws + F_YB2;
  float* cd = ws + F_CD;

  dim3 blk(256);
  // ---- sf chain ----
  conv_pc_k<<<dim3(PP / 256, 64), blk, 0, stream>>>(pc, IN(2), IN(3), Y1);
  stats_k<<<64, blk, 0, stream>>>(Y1, PP, SC(L_C1), SH(L_C1));
  conv_gemm_k<<<dim3(1, PP / 64), blk, 0, stream>>>(Y1, PP, IN(4), 64, 64, IN(5),
      SC(L_C1), SH(L_C1), 1, Y2, PP);
  stats_k<<<64, blk, 0, stream>>>(Y2, PP, SC(L_C2), SH(L_C2));
  conv_gemm_k<<<dim3(1, PP / 64), blk, 0, stream>>>(Y2, PP, IN(6), 64, 64, IN(7),
      SC(L_C2), SH(L_C2), 1, Y3, PP);
  stats_k<<<64, blk, 0, stream>>>(Y3, PP, SC(L_C3), SH(L_C3));
  gemm_big_k<false><<<dim3(1, PP / 128), blk, 0, stream>>>(Y3, PP, IN(8), 64, 64, IN(9),
      SC(L_C3), SH(L_C3), 1, nullptr, Y4, PP, nullptr, nullptr, nullptr, 0);
  stats_k<<<128, blk, 0, stream>>>(Y4, PP, SC(L_C4), SH(L_C4));
  gemm_big_k<true><<<dim3(8, PP / 128), blk, 0, stream>>>(Y4, PP, IN(10), 128, 128, IN(11),
      SC(L_C4), SH(L_C4), 1, nullptr, nullptr, PP, P5s, P5q, P5m, 1024);
  stats_reduce_k<<<4, blk, 0, stream>>>(P5s, P5q, PP / 128, 1024, 1.0 / PP, SC(L_C5),
                                        SH(L_C5));
  onehot_k<<<1, 96, 0, stream>>>(oh, gvec, gvt, gvb);
  maxpool_g_k<<<(32 * 1024) / 256, blk, 0, stream>>>(P5m, 16, 1024, SC(L_C5), SH(L_C5), 0,
                                                     gvec, 1027, 3);
  gdot_k<<<64, blk, 0, stream>>>(IN(12), gvec, gdot);
  // ---- seg head ----
  gemm_big_k<false><<<dim3(4, PP / 128), blk, 0, stream>>>(Y2, PP, IN(12) + 1027, 1091, 64,
      IN(13), SC(L_C2), SH(L_C2), 1, gdot, S1, PP, nullptr, nullptr, nullptr, 0);
  stats_k<<<512, blk, 0, stream>>>(S1, PP, SC(L_S1), SH(L_S1));
  gemm_big_k<false><<<dim3(2, PP / 128), blk, 0, stream>>>(S1, PP, IN(14), 512, 512, IN(15),
      SC(L_S1), SH(L_S1), 1, nullptr, S2, PP, nullptr, nullptr, nullptr, 0);
  stats_k<<<256, blk, 0, stream>>>(S2, PP, SC(L_S2), SH(L_S2));
  gemm_big_k<false><<<dim3(1, PP / 128), blk, 0, stream>>>(S2, PP, IN(16), 256, 256, IN(17),
      SC(L_S2), SH(L_S2), 1, nullptr, S3, PP, nullptr, nullptr, nullptr, 0);
  stats_k<<<128, blk, 0, stream>>>(S3, PP, SC(L_S3), SH(L_S3));
  gemm_big_k<false><<<dim3(1, PP / 128), blk, 0, stream>>>(S3, PP, IN(18), 128, 128, IN(19),
      SC(L_S3), SH(L_S3), 1, nullptr, S4, PP, nullptr, nullptr, nullptr, 0);
  stats_k<<<128, blk, 0, stream>>>(S4, PP, SC(L_S4), SH(L_S4));
  logits_k<<<PP / 256, blk, 0, stream>>>(S4, IN(20), IN(21), SC(L_S4), SH(L_S4), out, mask);
  compact_k<<<32, blk, 0, stream>>>(mask, pc, midx, cnt, meanv);
  sample_k<<<64, blk, 0, stream>>>(pc, midx, cnt, meanv, obj);
  // ---- t-net ----
  conv_k3_k<<<dim3(PP2 / 256, 128), blk, 0, stream>>>(obj, IN(22), IN(23), nullptr, T1);
  stats_k<<<128, blk, 0, stream>>>(T1, PP2, SC(L_T1), SH(L_T1));
  gemm_big_k<false><<<dim3(2, PP2 / 128), blk, 0, stream>>>(T1, PP2, IN(24), 128, 128,
      IN(25), SC(L_T1), SH(L_T1), 1, nullptr, T2, PP2, nullptr, nullptr, nullptr, 0);
  stats_k<<<256, blk, 0, stream>>>(T2, PP2, SC(L_T2), SH(L_T2));
  gemm_big_k<true><<<dim3(4, PP2 / 128), blk, 0, stream>>>(T2, PP2, IN(26), 256, 256,
      IN(27), SC(L_T2), SH(L_T2), 1, nullptr, nullptr, PP2, PTs, PTq, PTm, 512);
  stats_reduce_k<<<2, blk, 0, stream>>>(PTs, PTq, PP2 / 128, 512, 1.0 / PP2, SC(L_T3),
                                        SH(L_T3));
  maxpool_g_k<<<(32 * 512) / 256, blk, 0, stream>>>(PTm, 4, 512, SC(L_T3), SH(L_T3), 1, gvt,
                                                    515, 3);
  fc_gemm_k<<<dim3(1, 32), blk, 0, stream>>>(gvt, 515, 515, IN(28), IN(29), nullptr, nullptr,
                                             0, yt1, 256, 0, 256);
  fc_stats_k<<<1, blk, 0, stream>>>(yt1, 256, 256, SC(L_FT1), SH(L_FT1));
  fc_gemm_k<<<dim3(1, 32), blk, 0, stream>>>(yt1, 256, 256, IN(30), IN(31), SC(L_FT1),
                                             SH(L_FT1), 1, yt2, 128, 0, 128);
  fc_stats_k<<<1, blk, 0, stream>>>(yt2, 128, 128, SC(L_FT2), SH(L_FT2));
  fc_gemm_k<<<dim3(1, 32), blk, 0, stream>>>(yt2, 128, 128, IN(32), IN(33), SC(L_FT2),
                                             SH(L_FT2), 1, cd, 3, 0, 3);
  // ---- box net ----
  conv_k3_k<<<dim3(PP2 / 256, 128), blk, 0, stream>>>(obj, IN(34), IN(35), cd, Bb1);
  stats_k<<<128, blk, 0, stream>>>(Bb1, PP2, SC(L_B1), SH(L_B1));
  gemm_big_k<false><<<dim3(1, PP2 / 128), blk, 0, stream>>>(Bb1, PP2, IN(36), 128, 128,
      IN(37), SC(L_B1), SH(L_B1), 1, nullptr, Bb2, PP2, nullptr, nullptr, nullptr, 0);
  stats_k<<<128, blk, 0, stream>>>(Bb2, PP2, SC(L_B2), SH(L_B2));
  gemm_big_k<false><<<dim3(2, PP2 / 128), blk, 0, stream>>>(Bb2, PP2, IN(38), 128, 128,
      IN(39), SC(L_B2), SH(L_B2), 1, nullptr, Bb3, PP2, nullptr, nullptr, nullptr, 0);
  stats_k<<<256, blk, 0, stream>>>(Bb3, PP2, SC(L_B3), SH(L_B3));
  gemm_big_k<true><<<dim3(4, PP2 / 128), blk, 0, stream>>>(Bb3, PP2, IN(40), 256, 256,
      IN(41), SC(L_B3), SH(L_B3), 1, nullptr, nullptr, PP2, PBs, PBq, PBm, 512);
  stats_reduce_k<<<2, blk, 0, stream>>>(PBs, PBq, PP2 / 128, 512, 1.0 / PP2, SC(L_B4),
                                        SH(L_B4));
  maxpool_g_k<<<(32 * 512) / 256, blk, 0, stream>>>(PBm, 4, 512, SC(L_B4), SH(L_B4), 1, gvb,
                                                    515, 0);
  fc_gemm_k<<<dim3(2, 32), blk, 0, stream>>>(gvb, 515, 515, IN(42), IN(43), nullptr, nullptr,
                                             0, yb1, 512, 0, 512);
  fc_stats_k<<<2, blk, 0, stream>>>(yb1, 512, 512, SC(L_FB1), SH(L_FB1));
  fc_gemm_k<<<dim3(1, 32), blk, 0, stream>>>(yb1, 512, 512, IN(44), IN(45), SC(L_FB1),
                                             SH(L_FB1), 1, yb2, 256, 0, 256);
  fc_stats_k<<<1, blk, 0, stream>>>(yb2, 256, 256, SC(L_FB2), SH(L_FB2));
  fc_gemm_k<<<dim3(1, 32), blk, 0, stream>>>(yb2, 256, 256, IN(46), IN(47), SC(L_FB2),
                                             SH(L_FB2), 1, out, OUTW, 4096, 59);
  center_k<<<1, 96, 0, stream>>>(out, cd, meanv);
#undef IN
}